// Round 10
// baseline (5430.909 us; speedup 1.0000x reference)
//
#include <hip/hip_runtime.h>
#include <hip/hip_bf16.h>
#include <math.h>

#define BB 64
#define IMG 224
#define PP 16
#define CIN 3
#define DM 192
#define DEPTH 24
#define DSTATE 16
#define DINNER 384
#define DTR 12
#define DCONV 4
#define NP 196              // (224/16)^2
#define RTOT (BB * NP)      // 12544 rows
#define CHUNKS 14
#define LC 14               // NP / CHUNKS

typedef short bf16x8 __attribute__((ext_vector_type(8)));
typedef float f32x4 __attribute__((ext_vector_type(4)));

__device__ inline unsigned short f2bf_rne(float f) {
    unsigned u = __float_as_uint(f);
    unsigned r = u + 0x7fffu + ((u >> 16) & 1u);
    return (unsigned short)(r >> 16);
}
__device__ inline float bf2f(unsigned short s) {
    return __uint_as_float(((unsigned)s) << 16);
}

// ---------------- im2col for patch embed, emitting packed hi/lo bf16 planes ----------------
__global__ __launch_bounds__(256) void im2col_pack_kernel(const float* __restrict__ img,
                                                          short* __restrict__ colH,
                                                          short* __restrict__ colL) {
    size_t idx = (size_t)blockIdx.x * 256 + threadIdx.x;
    if (idx >= (size_t)RTOT * 768) return;
    int t = (int)(idx % 768);
    size_t r = idx / 768;
    int l = (int)(r % NP);
    int b = (int)(r / NP);
    int ph = l / 14, pw = l % 14;
    int ci = t / 256, rem = t % 256;
    int i = rem / 16, j = rem % 16;
    float v = img[(((size_t)b * CIN + ci) * IMG + ph * 16 + i) * IMG + pw * 16 + j];
    unsigned short hs = f2bf_rne(v);
    colH[idx] = (short)hs;
    colL[idx] = (short)f2bf_rne(v - bf2f(hs));
}

// ---------------- weight pack: fp32[NE] -> hi/lo bf16 planes ----------------
__global__ __launch_bounds__(256) void pack_w_kernel(const float* __restrict__ W,
                                                     short* __restrict__ Wh,
                                                     short* __restrict__ Wl, int NE) {
    int i = blockIdx.x * 256 + threadIdx.x;
    if (i * 4 >= NE) return;
    float4 v = *(const float4*)&W[i * 4];
    short4 h, l;
    unsigned short hs;
    hs = f2bf_rne(v.x); h.x = (short)hs; l.x = (short)f2bf_rne(v.x - bf2f(hs));
    hs = f2bf_rne(v.y); h.y = (short)hs; l.y = (short)f2bf_rne(v.y - bf2f(hs));
    hs = f2bf_rne(v.z); h.z = (short)hs; l.z = (short)f2bf_rne(v.z - bf2f(hs));
    hs = f2bf_rne(v.w); h.w = (short)hs; l.w = (short)f2bf_rne(v.w - bf2f(hs));
    *(short4*)&Wh[i * 4] = h;
    *(short4*)&Wl[i * 4] = l;
}

// ---------------- DIRECT-fragment bf16 hi/lo MFMA GEMM: C = A * B^T, no LDS ----------------
// A,B packed hi/lo planes (row stride K shorts). 256 threads = 4 independent waves,
// wave wq owns 64 x 32 tile at (row0, blockIdx.x*128 + wq*32). Fragments loaded
// straight from global (L1/L2-served); fp32 acc; D += Ah*Bh + Ah*Bl + Al*Bh.
// blockIdx.z = split-K slice (length Kc). gridDim.z==1: direct (+bias); else
// partial z at C + z*M*N. Needs M%64==0, Kc%32==0; N masked per-lane.
__global__ __launch_bounds__(256) void gemm_dir_kernel(const short* __restrict__ Ah,
                                                       const short* __restrict__ Al,
                                                       const short* __restrict__ Bh,
                                                       const short* __restrict__ Bl,
                                                       float* __restrict__ C,
                                                       const float* __restrict__ bias,
                                                       int M, int N, int K, int Kc) {
    const int lane = threadIdx.x & 63;
    const int wq = threadIdx.x >> 6;            // 0..3 col slice
    const int row0 = blockIdx.y * 64;
    const int col0 = blockIdx.x * 128 + wq * 32;
    const int kbase = blockIdx.z * Kc;
    const int fr = lane & 15;                   // frag row/col
    const int kg = (lane >> 4) * 8;             // k offset within K=32 step

    f32x4 acc[4][2] = {};
    const bf16x8 ZV = {0, 0, 0, 0, 0, 0, 0, 0};

    const short* aH0 = Ah + (size_t)(row0 + fr) * K + kbase + kg;
    const short* aL0 = Al + (size_t)(row0 + fr) * K + kbase + kg;
    const int gn0 = col0 + fr, gn1 = col0 + 16 + fr;
    const bool v0 = gn0 < N, v1 = gn1 < N;
    const short* bH0 = Bh + (size_t)(v0 ? gn0 : 0) * K + kbase + kg;
    const short* bL0 = Bl + (size_t)(v0 ? gn0 : 0) * K + kbase + kg;
    const short* bH1 = Bh + (size_t)(v1 ? gn1 : 0) * K + kbase + kg;
    const short* bL1 = Bl + (size_t)(v1 ? gn1 : 0) * K + kbase + kg;

    for (int t = 0; t < Kc; t += 32) {
        bf16x8 aH[4], aL[4], bH[2], bL[2];
#pragma unroll
        for (int i = 0; i < 4; i++) {
            aH[i] = *(const bf16x8*)(aH0 + (size_t)i * 16 * K + t);
            aL[i] = *(const bf16x8*)(aL0 + (size_t)i * 16 * K + t);
        }
        bH[0] = v0 ? *(const bf16x8*)(bH0 + t) : ZV;
        bL[0] = v0 ? *(const bf16x8*)(bL0 + t) : ZV;
        bH[1] = v1 ? *(const bf16x8*)(bH1 + t) : ZV;
        bL[1] = v1 ? *(const bf16x8*)(bL1 + t) : ZV;
#pragma unroll
        for (int i = 0; i < 4; i++)
#pragma unroll
            for (int j = 0; j < 2; j++) {
                acc[i][j] = __builtin_amdgcn_mfma_f32_16x16x32_bf16(aH[i], bH[j], acc[i][j], 0, 0, 0);
                acc[i][j] = __builtin_amdgcn_mfma_f32_16x16x32_bf16(aH[i], bL[j], acc[i][j], 0, 0, 0);
                acc[i][j] = __builtin_amdgcn_mfma_f32_16x16x32_bf16(aL[i], bH[j], acc[i][j], 0, 0, 0);
            }
    }

    float* Cout = C + (size_t)blockIdx.z * M * N;
    const bool direct = (gridDim.z == 1);
    const int crow = (lane >> 4) * 4;
    const int ccol = lane & 15;
#pragma unroll
    for (int i = 0; i < 4; i++)
#pragma unroll
        for (int j = 0; j < 2; j++) {
            int gn = col0 + j * 16 + ccol;
            if (gn >= N) continue;
            int gm0 = row0 + i * 16 + crow;
            float bv = (direct && bias) ? bias[gn] : 0.f;
#pragma unroll
            for (int reg = 0; reg < 4; reg++)
                Cout[(size_t)(gm0 + reg) * N + gn] = acc[i][j][reg] + bv;
        }
}

// ---------------- split-K reduce: sum parts (+bias); fp32 OR packed hi/lo output ----------------
__global__ __launch_bounds__(256) void reduce_kernel(const float* __restrict__ parts,
                                                     float* __restrict__ Cf,
                                                     short* __restrict__ outH,
                                                     short* __restrict__ outL,
                                                     const float* __restrict__ bias,
                                                     long MN, int N, int SK) {
    long i = (long)blockIdx.x * 256 + threadIdx.x;      // float4 index
    if (i * 4 >= MN) return;
    float4 acc = *(const float4*)&parts[i * 4];
    for (int z = 1; z < SK; z++) {
        float4 v = *(const float4*)&parts[(size_t)z * MN + i * 4];
        acc.x += v.x; acc.y += v.y; acc.z += v.z; acc.w += v.w;
    }
    if (bias) {
        int col = (int)((i * 4) % N);
        float4 bv = *(const float4*)&bias[col];
        acc.x += bv.x; acc.y += bv.y; acc.z += bv.z; acc.w += bv.w;
    }
    if (outH) {
        short4 h, l;
        unsigned short hs;
        hs = f2bf_rne(acc.x); h.x = (short)hs; l.x = (short)f2bf_rne(acc.x - bf2f(hs));
        hs = f2bf_rne(acc.y); h.y = (short)hs; l.y = (short)f2bf_rne(acc.y - bf2f(hs));
        hs = f2bf_rne(acc.z); h.z = (short)hs; l.z = (short)f2bf_rne(acc.z - bf2f(hs));
        hs = f2bf_rne(acc.w); h.w = (short)hs; l.w = (short)f2bf_rne(acc.w - bf2f(hs));
        *(short4*)&outH[i * 4] = h;
        *(short4*)&outL[i * 4] = l;
    } else {
        *(float4*)&Cf[i * 4] = acc;
    }
}

// ---------------- causal depthwise conv (DCONV=4) + SiLU; emits fp32 + packed planes ----------------
__global__ __launch_bounds__(256) void conv_silu_kernel(const float* __restrict__ xz,
                                                        const float* __restrict__ cw,
                                                        const float* __restrict__ cb,
                                                        float* __restrict__ xc,
                                                        short* __restrict__ xcH,
                                                        short* __restrict__ xcL) {
    size_t idx = (size_t)blockIdx.x * 256 + threadIdx.x;
    if (idx >= (size_t)RTOT * DINNER) return;
    int e = (int)(idx % DINNER);
    size_t r = idx / DINNER;
    int l = (int)(r % NP);
    size_t b = r / NP;
    const float* w = cw + (size_t)e * DCONV;
    float acc = cb[e];
#pragma unroll
    for (int k = 0; k < DCONV; k++) {
        int ls = l + k - (DCONV - 1);
        if (ls >= 0) acc += xz[(b * NP + ls) * 768 + e] * w[k];
    }
    float val = acc / (1.f + __expf(-acc));   // silu (fast exp)
    xc[idx] = val;
    unsigned short hs = f2bf_rne(val);
    xcH[idx] = (short)hs;
    xcL[idx] = (short)f2bf_rne(val - bf2f(hs));
}

// ---------------- dt projection + softplus -> dead xs-half of xz ----------------
__global__ __launch_bounds__(256) void dt_kernel(const float* __restrict__ proj,
                                                 const float* __restrict__ dtw,
                                                 const float* __restrict__ dtb,
                                                 float* __restrict__ xz) {
    int idx = blockIdx.x * 256 + threadIdx.x;
    if (idx >= RTOT * DINNER) return;
    int d = idx % DINNER;
    size_t r = (size_t)idx / DINNER;
    const float* pr = proj + r * 44;
    const float* w = dtw + (size_t)d * DTR;
    float acc = dtb[d];
#pragma unroll
    for (int k = 0; k < DTR; k++) acc += pr[k] * w[k];
    xz[r * 768 + d] = (acc > 20.f) ? acc : __logf(1.f + __expf(acc));
}

// ---------------- chunked selective scan: lane owns (b,d), 16 states in regs ----------------
__global__ __launch_bounds__(128) void scanA_kernel(const float* __restrict__ xc,
                                                    const float* __restrict__ proj,
                                                    const float* __restrict__ xz,
                                                    const float* __restrict__ A_log,
                                                    float* __restrict__ hEnd,
                                                    float* __restrict__ prodDA) {
    int d = blockIdx.x * 128 + threadIdx.x;       // grid.x = 3
    int c = blockIdx.y, b = blockIdx.z;
    float a[DSTATE], h[DSTATE], p[DSTATE];
#pragma unroll
    for (int s = 0; s < DSTATE; s++) {
        a[s] = -expf(A_log[(size_t)d * DSTATE + s]);   // precise (once per lane)
        h[s] = 0.f;
        p[s] = 1.f;
    }
    size_t rbase = (size_t)b * NP + (size_t)c * LC;
    for (int l = 0; l < LC; l++) {
        size_t r = rbase + l;
        float dtv = xz[r * 768 + d];              // dt (stored in xs-half)
        float du = dtv * xc[r * DINNER + d];
        const float* pb = proj + r * 44 + DTR;    // wave-uniform
        float Bv[DSTATE];
        *(float4*)&Bv[0]  = *(const float4*)&pb[0];
        *(float4*)&Bv[4]  = *(const float4*)&pb[4];
        *(float4*)&Bv[8]  = *(const float4*)&pb[8];
        *(float4*)&Bv[12] = *(const float4*)&pb[12];
#pragma unroll
        for (int s = 0; s < DSTATE; s++) {
            float dA = __expf(dtv * a[s]);        // fast exp (hot loop)
            h[s] = h[s] * dA + du * Bv[s];
            p[s] *= dA;
        }
    }
    float* he = hEnd   + (((size_t)b * CHUNKS + c) * DINNER + d) * DSTATE;
    float* pd = prodDA + (((size_t)b * CHUNKS + c) * DINNER + d) * DSTATE;
#pragma unroll
    for (int g = 0; g < 4; g++) {
        *(float4*)&he[g * 4] = *(float4*)&h[g * 4];
        *(float4*)&pd[g * 4] = *(float4*)&p[g * 4];
    }
}

__global__ __launch_bounds__(256) void scanB_kernel(const float* __restrict__ hEnd,
                                                    float* __restrict__ prodDA) {
    int idx = blockIdx.x * 256 + threadIdx.x;
    if (idx >= BB * DINNER * DSTATE) return;
    int b = idx / (DINNER * DSTATE);
    int rem = idx % (DINNER * DSTATE);
    float run = 0.f;
    for (int c = 0; c < CHUNKS; c++) {
        size_t off = ((size_t)b * CHUNKS + c) * (DINNER * DSTATE) + rem;
        float p = prodDA[off];
        float e = hEnd[off];
        prodDA[off] = run;          // hInit for chunk c
        run = run * p + e;
    }
}

// Pass C: rerun from hInit; fused (y+u*D)*silu(z); emits y2 PACKED hi/lo planes.
__global__ __launch_bounds__(128) void scanC_kernel(const float* __restrict__ xc,
                                                    const float* __restrict__ proj,
                                                    const float* __restrict__ hInit,
                                                    const float* __restrict__ A_log,
                                                    const float* __restrict__ Dv,
                                                    const float* __restrict__ xz,
                                                    short* __restrict__ yh,
                                                    short* __restrict__ yl) {
    int d = blockIdx.x * 128 + threadIdx.x;       // grid.x = 3
    int c = blockIdx.y, b = blockIdx.z;
    float a[DSTATE], h[DSTATE];
#pragma unroll
    for (int s = 0; s < DSTATE; s++)
        a[s] = -expf(A_log[(size_t)d * DSTATE + s]);   // precise (once per lane)
    const float* hi = hInit + (((size_t)b * CHUNKS + c) * DINNER + d) * DSTATE;
#pragma unroll
    for (int g = 0; g < 4; g++)
        *(float4*)&h[g * 4] = *(const float4*)&hi[g * 4];
    float Dd = Dv[d];
    size_t rbase = (size_t)b * NP + (size_t)c * LC;
    for (int l = 0; l < LC; l++) {
        size_t r = rbase + l;
        float dtv = xz[r * 768 + d];              // dt (stored in xs-half)
        float u = xc[r * DINNER + d];
        float du = dtv * u;
        const float* pb = proj + r * 44 + DTR;              // wave-uniform
        const float* pc = proj + r * 44 + DTR + DSTATE;
        float Bv[DSTATE], Cv[DSTATE];
        *(float4*)&Bv[0]  = *(const float4*)&pb[0];
        *(float4*)&Bv[4]  = *(const float4*)&pb[4];
        *(float4*)&Bv[8]  = *(const float4*)&pb[8];
        *(float4*)&Bv[12] = *(const float4*)&pb[12];
        *(float4*)&Cv[0]  = *(const float4*)&pc[0];
        *(float4*)&Cv[4]  = *(const float4*)&pc[4];
        *(float4*)&Cv[8]  = *(const float4*)&pc[8];
        *(float4*)&Cv[12] = *(const float4*)&pc[12];
        float y = 0.f;
#pragma unroll
        for (int s = 0; s < DSTATE; s++) {
            float dA = __expf(dtv * a[s]);        // fast exp (hot loop)
            h[s] = h[s] * dA + du * Bv[s];
            y = fmaf(h[s], Cv[s], y);
        }
        float z = xz[r * 768 + DINNER + d];
        float val = (y + u * Dd) * (z / (1.f + __expf(-z)));
        unsigned short hs = f2bf_rne(val);
        yh[r * DINNER + d] = (short)hs;
        yl[r * DINNER + d] = (short)f2bf_rne(val - bf2f(hs));
    }
}

// ---------------- final layernorm: per-row stats (packed x input) ----------------
__global__ __launch_bounds__(256) void ln_stats_kernel(const short* __restrict__ xh,
                                                       const short* __restrict__ xl,
                                                       float* __restrict__ stats) {
    int r = blockIdx.x * 4 + (threadIdx.x >> 6);
    int lane = threadIdx.x & 63;
    if (r >= RTOT) return;
    float s = 0.f, ss = 0.f;
    for (int c = lane; c < DM; c += 64) {
        size_t i = (size_t)r * DM + c;
        float v = bf2f((unsigned short)xh[i]) + bf2f((unsigned short)xl[i]);
        s += v;
        ss += v * v;
    }
#pragma unroll
    for (int o = 32; o > 0; o >>= 1) {
        s += __shfl_down(s, o);
        ss += __shfl_down(ss, o);
    }
    if (lane == 0) {
        float mu = s / (float)DM;
        float var = ss / (float)DM - mu * mu;
        stats[r * 2] = mu;
        stats[r * 2 + 1] = rsqrtf(var + 1e-5f);
    }
}

// ---------------- normalized mean over sequence (packed x input) ----------------
__global__ __launch_bounds__(256) void ln_mean_kernel(const short* __restrict__ xh,
                                                      const short* __restrict__ xl,
                                                      const float* __restrict__ stats,
                                                      const float* __restrict__ nw,
                                                      const float* __restrict__ nb,
                                                      float* __restrict__ out) {
    int idx = blockIdx.x * 256 + threadIdx.x;
    if (idx >= BB * DM) return;
    int c = idx % DM;
    int b = idx / DM;
    float acc = 0.f;
    for (int l = 0; l < NP; l++) {
        size_t r = (size_t)b * NP + l;
        size_t i = r * DM + c;
        float v = bf2f((unsigned short)xh[i]) + bf2f((unsigned short)xl[i]);
        acc += (v - stats[r * 2]) * stats[r * 2 + 1];
    }
    out[idx] = acc * (1.f / (float)NP) * nw[c] + nb[c];
}

extern "C" void kernel_launch(void* const* d_in, const int* in_sizes, int n_in,
                              void* d_out, int out_size, void* d_ws, size_t ws_size,
                              hipStream_t stream) {
    const float* img     = (const float*)d_in[0];
    const float* patch_w = (const float*)d_in[1];
    const float* patch_b = (const float*)d_in[2];
    const float* in_w    = (const float*)d_in[3];
    const float* conv_w  = (const float*)d_in[4];
    const float* conv_b  = (const float*)d_in[5];
    const float* xpw     = (const float*)d_in[6];
    const float* dtw     = (const float*)d_in[7];
    const float* dtb     = (const float*)d_in[8];
    const float* A_log   = (const float*)d_in[9];
    const float* Dv      = (const float*)d_in[10];
    const float* outw    = (const float*)d_in[11];
    const float* norm_w  = (const float*)d_in[12];
    const float* norm_b  = (const float*)d_in[13];
    float* out = (float*)d_out;

    float* ws = (float*)d_ws;
    const size_t R = RTOT;
    const size_t PLX = R * DM;                 // x plane: 2,408,448 shorts (xA/xB hold 2 planes = PLX floats)
    const size_t PLY = R * DINNER;             // y2/xc plane: 4,816,896 shorts
    const size_t SCN = (size_t)BB * CHUNKS * DINNER * DSTATE;   // 5,505,024 fu
    float* xA      = ws;                       // packed x planes (PLX fu)
    float* xB      = xA + PLX;                 // packed x planes
    float* xz      = xB + PLX;                 // R*768 fp32 (layers) / packed im2col (patch)
    float* xc      = xz + R * 768;             // R*384 fp32
    float* proj    = xc + R * DINNER;          // R*44 fp32
    float* scratch = proj + R * 44;            // 2*SCN shared region + weight packs + stats
    float* hEnd    = scratch;                  // SCN fu
    float* prodDA  = hEnd + SCN;               // SCN fu (becomes hInit)
    float* wpkA    = scratch + 2 * SCN;        // 147,456 fu (in_w / patch_w / xpw planes)
    float* wpkB    = wpkA + 147456;            // 73,728 fu (outw planes)
    float* stats   = wpkB + 73728;             // R*2

    short* y2h = (short*)scratch;              // y2 packed planes (dead hEnd region)
    short* y2l = y2h + PLY;
    float* pkparts = prodDA;                   // out_proj SK2 partials (dead hInit region)
    short* xcpkH = (short*)(scratch + 2 * SCN - (PLY / 2) * 2);  // xc packed planes, tail of prodDA region
    short* xcpkL = xcpkH + PLY;                // [6,193,152 .. 11,010,048) fu — dead before scanA

    // patch embed: pack patch_w + packed im2col + SK4 direct GEMM + packed reduce(+bias)
    {
        short* wh = (short*)wpkA; short* wl = wh + DM * 768;
        pack_w_kernel<<<dim3((DM * 768 / 4 + 255) / 256), 256, 0, stream>>>(
            patch_w, wh, wl, DM * 768);
        short* colH = (short*)xz; short* colL = colH + R * 768;
        size_t n = R * 768;
        im2col_pack_kernel<<<dim3((unsigned)((n + 255) / 256)), 256, 0, stream>>>(
            img, colH, colL);
        gemm_dir_kernel<<<dim3(2, RTOT / 64, 4), 256, 0, stream>>>(
            colH, colL, wh, wl, scratch, nullptr, RTOT, DM, 768, 192);
        long MN = (long)RTOT * DM;
        reduce_kernel<<<dim3((unsigned)((MN / 4 + 255) / 256)), 256, 0, stream>>>(
            scratch, nullptr, (short*)xA, (short*)xA + PLX, patch_b, MN, DM, 4);
    }

    float* xin = xA;
    float* xout = xB;
    for (int layer = 0; layer < DEPTH; layer++) {
        const float* in_w_l  = in_w + (size_t)layer * 2 * DINNER * DM;
        const float* conv_wl = conv_w + (size_t)layer * DINNER * DCONV;
        const float* conv_bl = conv_b + (size_t)layer * DINNER;
        const float* xpw_l   = xpw + (size_t)layer * (DTR + 2 * DSTATE) * DINNER;
        const float* dtw_l   = dtw + (size_t)layer * DINNER * DTR;
        const float* dtb_l   = dtb + (size_t)layer * DINNER;
        const float* Alog_l  = A_log + (size_t)layer * DINNER * DSTATE;
        const float* Dv_l    = Dv + (size_t)layer * DINNER;
        const float* outw_l  = outw + (size_t)layer * DM * DINNER;

        short* xinH = (short*)xin; short* xinL = xinH + PLX;
        short* xoutH = (short*)xout; short* xoutL = xoutH + PLX;

        // pack in_w, then xz = x @ in_w^T (M=12544, N=768, K=192), direct fp32 out
        {
            short* wh = (short*)wpkA; short* wl = wh + 2 * DINNER * DM;
            pack_w_kernel<<<dim3((2 * DINNER * DM / 4 + 255) / 256), 256, 0, stream>>>(
                in_w_l, wh, wl, 2 * DINNER * DM);
            gemm_dir_kernel<<<dim3(6, RTOT / 64, 1), 256, 0, stream>>>(
                xinH, xinL, wh, wl, xz, nullptr, RTOT, 2 * DINNER, DM, DM);
        }
        // xc = silu(causal depthwise conv(xs)); also emits packed xc planes
        {
            size_t n = R * DINNER;
            conv_silu_kernel<<<dim3((unsigned)((n + 255) / 256)), 256, 0, stream>>>(
                xz, conv_wl, conv_bl, xc, xcpkH, xcpkL);
        }
        // pack xpw (reuses wpkA — in_w planes are dead), then
        // proj = xc @ xpw^T (N=44, K=384) SK=4, Kc=96, direct GEMM on packed xc
        {
            short* wh = (short*)wpkA; short* wl = wh + 44 * DINNER;
            pack_w_kernel<<<dim3((44 * DINNER / 4 + 255) / 256), 256, 0, stream>>>(
                xpw_l, wh, wl, 44 * DINNER);
            gemm_dir_kernel<<<dim3(1, RTOT / 64, 4), 256, 0, stream>>>(
                xcpkH, xcpkL, wh, wl, scratch, nullptr, RTOT, DTR + 2 * DSTATE, DINNER, 96);
            long MN = (long)RTOT * 44;
            reduce_kernel<<<dim3((unsigned)((MN / 4 + 255) / 256)), 256, 0, stream>>>(
                scratch, proj, nullptr, nullptr, nullptr, MN, 44, 4);
        }
        // dt = softplus(...) -> xz xs-half
        dt_kernel<<<dim3((RTOT * DINNER + 255) / 256), 256, 0, stream>>>(
            proj, dtw_l, dtb_l, xz);
        // chunked scan; scanC emits y2 packed into dead hEnd region
        scanA_kernel<<<dim3(3, CHUNKS, BB), 128, 0, stream>>>(
            xc, proj, xz, Alog_l, hEnd, prodDA);
        scanB_kernel<<<dim3((BB * DINNER * DSTATE + 255) / 256), 256, 0, stream>>>(
            hEnd, prodDA);
        scanC_kernel<<<dim3(3, CHUNKS, BB), 128, 0, stream>>>(
            xc, proj, prodDA, Alog_l, Dv_l, xz, y2h, y2l);
        // pack outw, then x_next = y2 @ outw^T (N=192, K=384) SK=2, packed reduce -> xout
        {
            short* wh = (short*)wpkB; short* wl = wh + DM * DINNER;
            pack_w_kernel<<<dim3((DM * DINNER / 4 + 255) / 256), 256, 0, stream>>>(
                outw_l, wh, wl, DM * DINNER);
            gemm_dir_kernel<<<dim3(2, RTOT / 64, 2), 256, 0, stream>>>(
                y2h, y2l, wh, wl, pkparts, nullptr, RTOT, DM, DINNER, 192);
            long MN = (long)RTOT * DM;
            reduce_kernel<<<dim3((unsigned)((MN / 4 + 255) / 256)), 256, 0, stream>>>(
                pkparts, nullptr, xoutH, xoutL, nullptr, MN, DM, 2);
        }

        float* t = xin; xin = xout; xout = t;
    }

    // final layernorm + mean over sequence (packed x)
    short* xfH = (short*)xin; short* xfL = xfH + PLX;
    ln_stats_kernel<<<dim3(RTOT / 4), 256, 0, stream>>>(xfH, xfL, stats);
    ln_mean_kernel<<<dim3((BB * DM + 255) / 256), 256, 0, stream>>>(
        xfH, xfL, stats, norm_w, norm_b, out);
}

// Round 11
// 3962.667 us; speedup vs baseline: 1.3705x; 1.3705x over previous
//
#include <hip/hip_runtime.h>
#include <hip/hip_bf16.h>
#include <math.h>

#define BB 64
#define IMG 224
#define PP 16
#define CIN 3
#define DM 192
#define DEPTH 24
#define DSTATE 16
#define DINNER 384
#define DTR 12
#define DCONV 4
#define NP 196              // (224/16)^2
#define RTOT (BB * NP)      // 12544 rows
#define CHUNKS 14
#define LC 14               // NP / CHUNKS

typedef short bf16x8 __attribute__((ext_vector_type(8)));
typedef float f32x4 __attribute__((ext_vector_type(4)));

__device__ inline unsigned short f2bf_rne(float f) {
    unsigned u = __float_as_uint(f);
    unsigned r = u + 0x7fffu + ((u >> 16) & 1u);
    return (unsigned short)(r >> 16);
}
__device__ inline float bf2f(unsigned short s) {
    return __uint_as_float(((unsigned)s) << 16);
}

// ---------------- im2col for patch embed, emitting bf16 ----------------
__global__ __launch_bounds__(256) void im2col_pack_kernel(const float* __restrict__ img,
                                                          short* __restrict__ colH) {
    size_t idx = (size_t)blockIdx.x * 256 + threadIdx.x;
    if (idx >= (size_t)RTOT * 768) return;
    int t = (int)(idx % 768);
    size_t r = idx / 768;
    int l = (int)(r % NP);
    int b = (int)(r / NP);
    int ph = l / 14, pw = l % 14;
    int ci = t / 256, rem = t % 256;
    int i = rem / 16, j = rem % 16;
    float v = img[(((size_t)b * CIN + ci) * IMG + ph * 16 + i) * IMG + pw * 16 + j];
    colH[idx] = (short)f2bf_rne(v);
}

// ---------------- weight pack: fp32[NE] -> bf16 ----------------
__global__ __launch_bounds__(256) void pack_w_kernel(const float* __restrict__ W,
                                                     short* __restrict__ Wh, int NE) {
    int i = blockIdx.x * 256 + threadIdx.x;
    if (i * 4 >= NE) return;
    float4 v = *(const float4*)&W[i * 4];
    short4 h;
    h.x = (short)f2bf_rne(v.x);
    h.y = (short)f2bf_rne(v.y);
    h.z = (short)f2bf_rne(v.z);
    h.w = (short)f2bf_rne(v.w);
    *(short4*)&Wh[i * 4] = h;
}

// ---------------- single-plane bf16 MFMA GEMM: C[M,N] = A[M,K] * B[N,K]^T ----------------
// A,B pre-packed bf16, row stride K shorts. fp32 accumulate, 16x16x32 MFMA.
// BM=128, BK=32, 256 threads = 4 waves (2x2), wave tile 64 x BN/2.
// blockIdx.z = split-K slice (length Kc). gridDim.z==1: direct write (+bias);
// else partial z at C + z*M*N (reduced later). Needs M%128==0, Kc%32==0; B rows masked vs N.
template<int BN>
__global__ __launch_bounds__(256) void gemm_pk_kernel(const short* __restrict__ Ah,
                                                      const short* __restrict__ Bh,
                                                      float* __restrict__ C,
                                                      const float* __restrict__ bias,
                                                      int M, int N, int K, int Kc) {
    constexpr int BM = 128, BK = 32;
    constexpr int LDSS = BK + 8;                // 40 shorts = 80 B row stride
    constexpr int NF = BN / 32;                 // n-frags per wave
    constexpr int A8 = 2;                       // short8 loads/thread (A)
    constexpr int B8 = BN / 64;                 // short8 loads/thread (B)
    __shared__ short AsH[BM * LDSS];
    __shared__ short BsH[BN * LDSS];

    const int tid = threadIdx.x;
    const int lane = tid & 63;
    const int wid = tid >> 6;
    const int wr = wid >> 1, wc = wid & 1;      // 2x2 wave grid
    const int row0 = blockIdx.y * BM, col0 = blockIdx.x * BN;
    const int kbase = blockIdx.z * Kc;
    const bf16x8 ZV = {0, 0, 0, 0, 0, 0, 0, 0};

    bf16x8 aPh[A8], bPh[B8];
    f32x4 acc[4][NF] = {};

    auto loadG = [&](int k0) {
#pragma unroll
        for (int i = 0; i < A8; i++) {
            int lin = tid + i * 256;
            int r = lin >> 2, cg = (lin & 3) * 8;
            aPh[i] = *(const bf16x8*)&Ah[(size_t)(row0 + r) * K + k0 + cg];
        }
#pragma unroll
        for (int i = 0; i < B8; i++) {
            int lin = tid + i * 256;
            int r = lin >> 2, cg = (lin & 3) * 8;
            int n = col0 + r;
            bPh[i] = (n < N) ? *(const bf16x8*)&Bh[(size_t)n * K + k0 + cg] : ZV;
        }
    };
    auto storeLDS = [&]() {
#pragma unroll
        for (int i = 0; i < A8; i++) {
            int lin = tid + i * 256;
            int r = lin >> 2, cg = (lin & 3) * 8;
            *(bf16x8*)&AsH[r * LDSS + cg] = aPh[i];
        }
#pragma unroll
        for (int i = 0; i < B8; i++) {
            int lin = tid + i * 256;
            int r = lin >> 2, cg = (lin & 3) * 8;
            *(bf16x8*)&BsH[r * LDSS + cg] = bPh[i];
        }
    };

    loadG(kbase);
    storeLDS();
    __syncthreads();
    for (int k0 = kbase + BK;; k0 += BK) {
        const bool has_next = (k0 < kbase + Kc);
        if (has_next) loadG(k0);                // next-tile loads in flight
        {
            const int fr = lane & 15;           // row within 16-frag
            const int kg = (lane >> 4) * 8;     // k offset within BK=32
            bf16x8 aH[4], bH[NF];
#pragma unroll
            for (int i = 0; i < 4; i++)
                aH[i] = *(const bf16x8*)&AsH[(wr * 64 + i * 16 + fr) * LDSS + kg];
#pragma unroll
            for (int j = 0; j < NF; j++)
                bH[j] = *(const bf16x8*)&BsH[(wc * (BN / 2) + j * 16 + fr) * LDSS + kg];
#pragma unroll
            for (int i = 0; i < 4; i++)
#pragma unroll
                for (int j = 0; j < NF; j++)
                    acc[i][j] = __builtin_amdgcn_mfma_f32_16x16x32_bf16(aH[i], bH[j], acc[i][j], 0, 0, 0);
        }
        if (!has_next) break;
        __syncthreads();
        storeLDS();
        __syncthreads();
    }

    float* Cout = C + (size_t)blockIdx.z * M * N;
    const bool direct = (gridDim.z == 1);
    const int crow = (lane >> 4) * 4;
    const int ccol = lane & 15;
#pragma unroll
    for (int i = 0; i < 4; i++)
#pragma unroll
        for (int j = 0; j < NF; j++) {
            int gn = col0 + wc * (BN / 2) + j * 16 + ccol;
            if (gn >= N) continue;
            int gm0 = row0 + wr * 64 + i * 16 + crow;
            float bv = (direct && bias) ? bias[gn] : 0.f;
#pragma unroll
            for (int reg = 0; reg < 4; reg++)
                Cout[(size_t)(gm0 + reg) * N + gn] = acc[i][j][reg] + bv;
        }
}

// ---------------- split-K reduce: sum parts (+bias); fp32 OR packed bf16 output ----------------
__global__ __launch_bounds__(256) void reduce_kernel(const float* __restrict__ parts,
                                                     float* __restrict__ Cf,
                                                     short* __restrict__ outH,
                                                     const float* __restrict__ bias,
                                                     long MN, int N, int SK) {
    long i = (long)blockIdx.x * 256 + threadIdx.x;      // float4 index
    if (i * 4 >= MN) return;
    float4 acc = *(const float4*)&parts[i * 4];
    for (int z = 1; z < SK; z++) {
        float4 v = *(const float4*)&parts[(size_t)z * MN + i * 4];
        acc.x += v.x; acc.y += v.y; acc.z += v.z; acc.w += v.w;
    }
    if (bias) {
        int col = (int)((i * 4) % N);
        float4 bv = *(const float4*)&bias[col];
        acc.x += bv.x; acc.y += bv.y; acc.z += bv.z; acc.w += bv.w;
    }
    if (outH) {
        short4 h;
        h.x = (short)f2bf_rne(acc.x);
        h.y = (short)f2bf_rne(acc.y);
        h.z = (short)f2bf_rne(acc.z);
        h.w = (short)f2bf_rne(acc.w);
        *(short4*)&outH[i * 4] = h;
    } else {
        *(float4*)&Cf[i * 4] = acc;
    }
}

// ---------------- causal depthwise conv (DCONV=4) + SiLU; emits fp32 + bf16 ----------------
__global__ __launch_bounds__(256) void conv_silu_kernel(const float* __restrict__ xz,
                                                        const float* __restrict__ cw,
                                                        const float* __restrict__ cb,
                                                        float* __restrict__ xc,
                                                        short* __restrict__ xcH) {
    size_t idx = (size_t)blockIdx.x * 256 + threadIdx.x;
    if (idx >= (size_t)RTOT * DINNER) return;
    int e = (int)(idx % DINNER);
    size_t r = idx / DINNER;
    int l = (int)(r % NP);
    size_t b = r / NP;
    const float* w = cw + (size_t)e * DCONV;
    float acc = cb[e];
#pragma unroll
    for (int k = 0; k < DCONV; k++) {
        int ls = l + k - (DCONV - 1);
        if (ls >= 0) acc += xz[(b * NP + ls) * 768 + e] * w[k];
    }
    float val = acc / (1.f + __expf(-acc));   // silu (fast exp)
    xc[idx] = val;
    xcH[idx] = (short)f2bf_rne(val);
}

// ---------------- dt projection + softplus -> dead xs-half of xz ----------------
__global__ __launch_bounds__(256) void dt_kernel(const float* __restrict__ proj,
                                                 const float* __restrict__ dtw,
                                                 const float* __restrict__ dtb,
                                                 float* __restrict__ xz) {
    int idx = blockIdx.x * 256 + threadIdx.x;
    if (idx >= RTOT * DINNER) return;
    int d = idx % DINNER;
    size_t r = (size_t)idx / DINNER;
    const float* pr = proj + r * 44;
    const float* w = dtw + (size_t)d * DTR;
    float acc = dtb[d];
#pragma unroll
    for (int k = 0; k < DTR; k++) acc += pr[k] * w[k];
    xz[r * 768 + d] = (acc > 20.f) ? acc : __logf(1.f + __expf(acc));
}

// ---------------- chunked selective scan: lane owns (b,d), 16 states in regs ----------------
__global__ __launch_bounds__(128) void scanA_kernel(const float* __restrict__ xc,
                                                    const float* __restrict__ proj,
                                                    const float* __restrict__ xz,
                                                    const float* __restrict__ A_log,
                                                    float* __restrict__ hEnd,
                                                    float* __restrict__ prodDA) {
    int d = blockIdx.x * 128 + threadIdx.x;       // grid.x = 3
    int c = blockIdx.y, b = blockIdx.z;
    float a[DSTATE], h[DSTATE], p[DSTATE];
#pragma unroll
    for (int s = 0; s < DSTATE; s++) {
        a[s] = -expf(A_log[(size_t)d * DSTATE + s]);   // precise (once per lane)
        h[s] = 0.f;
        p[s] = 1.f;
    }
    size_t rbase = (size_t)b * NP + (size_t)c * LC;
    for (int l = 0; l < LC; l++) {
        size_t r = rbase + l;
        float dtv = xz[r * 768 + d];              // dt (stored in xs-half)
        float du = dtv * xc[r * DINNER + d];
        const float* pb = proj + r * 44 + DTR;    // wave-uniform
        float Bv[DSTATE];
        *(float4*)&Bv[0]  = *(const float4*)&pb[0];
        *(float4*)&Bv[4]  = *(const float4*)&pb[4];
        *(float4*)&Bv[8]  = *(const float4*)&pb[8];
        *(float4*)&Bv[12] = *(const float4*)&pb[12];
#pragma unroll
        for (int s = 0; s < DSTATE; s++) {
            float dA = __expf(dtv * a[s]);        // fast exp (hot loop)
            h[s] = h[s] * dA + du * Bv[s];
            p[s] *= dA;
        }
    }
    float* he = hEnd   + (((size_t)b * CHUNKS + c) * DINNER + d) * DSTATE;
    float* pd = prodDA + (((size_t)b * CHUNKS + c) * DINNER + d) * DSTATE;
#pragma unroll
    for (int g = 0; g < 4; g++) {
        *(float4*)&he[g * 4] = *(float4*)&h[g * 4];
        *(float4*)&pd[g * 4] = *(float4*)&p[g * 4];
    }
}

__global__ __launch_bounds__(256) void scanB_kernel(const float* __restrict__ hEnd,
                                                    float* __restrict__ prodDA) {
    int idx = blockIdx.x * 256 + threadIdx.x;
    if (idx >= BB * DINNER * DSTATE) return;
    int b = idx / (DINNER * DSTATE);
    int rem = idx % (DINNER * DSTATE);
    float run = 0.f;
    for (int c = 0; c < CHUNKS; c++) {
        size_t off = ((size_t)b * CHUNKS + c) * (DINNER * DSTATE) + rem;
        float p = prodDA[off];
        float e = hEnd[off];
        prodDA[off] = run;          // hInit for chunk c
        run = run * p + e;
    }
}

// Pass C: rerun from hInit; fused (y+u*D)*silu(z); emits y2 as bf16.
__global__ __launch_bounds__(128) void scanC_kernel(const float* __restrict__ xc,
                                                    const float* __restrict__ proj,
                                                    const float* __restrict__ hInit,
                                                    const float* __restrict__ A_log,
                                                    const float* __restrict__ Dv,
                                                    const float* __restrict__ xz,
                                                    short* __restrict__ yh) {
    int d = blockIdx.x * 128 + threadIdx.x;       // grid.x = 3
    int c = blockIdx.y, b = blockIdx.z;
    float a[DSTATE], h[DSTATE];
#pragma unroll
    for (int s = 0; s < DSTATE; s++)
        a[s] = -expf(A_log[(size_t)d * DSTATE + s]);   // precise (once per lane)
    const float* hi = hInit + (((size_t)b * CHUNKS + c) * DINNER + d) * DSTATE;
#pragma unroll
    for (int g = 0; g < 4; g++)
        *(float4*)&h[g * 4] = *(const float4*)&hi[g * 4];
    float Dd = Dv[d];
    size_t rbase = (size_t)b * NP + (size_t)c * LC;
    for (int l = 0; l < LC; l++) {
        size_t r = rbase + l;
        float dtv = xz[r * 768 + d];              // dt (stored in xs-half)
        float u = xc[r * DINNER + d];
        float du = dtv * u;
        const float* pb = proj + r * 44 + DTR;              // wave-uniform
        const float* pc = proj + r * 44 + DTR + DSTATE;
        float Bv[DSTATE], Cv[DSTATE];
        *(float4*)&Bv[0]  = *(const float4*)&pb[0];
        *(float4*)&Bv[4]  = *(const float4*)&pb[4];
        *(float4*)&Bv[8]  = *(const float4*)&pb[8];
        *(float4*)&Bv[12] = *(const float4*)&pb[12];
        *(float4*)&Cv[0]  = *(const float4*)&pc[0];
        *(float4*)&Cv[4]  = *(const float4*)&pc[4];
        *(float4*)&Cv[8]  = *(const float4*)&pc[8];
        *(float4*)&Cv[12] = *(const float4*)&pc[12];
        float y = 0.f;
#pragma unroll
        for (int s = 0; s < DSTATE; s++) {
            float dA = __expf(dtv * a[s]);        // fast exp (hot loop)
            h[s] = h[s] * dA + du * Bv[s];
            y = fmaf(h[s], Cv[s], y);
        }
        float z = xz[r * 768 + DINNER + d];
        float val = (y + u * Dd) * (z / (1.f + __expf(-z)));
        yh[r * DINNER + d] = (short)f2bf_rne(val);
    }
}

// ---------------- final layernorm: per-row stats (bf16 x input) ----------------
__global__ __launch_bounds__(256) void ln_stats_kernel(const short* __restrict__ xh,
                                                       float* __restrict__ stats) {
    int r = blockIdx.x * 4 + (threadIdx.x >> 6);
    int lane = threadIdx.x & 63;
    if (r >= RTOT) return;
    float s = 0.f, ss = 0.f;
    for (int c = lane; c < DM; c += 64) {
        float v = bf2f((unsigned short)xh[(size_t)r * DM + c]);
        s += v;
        ss += v * v;
    }
#pragma unroll
    for (int o = 32; o > 0; o >>= 1) {
        s += __shfl_down(s, o);
        ss += __shfl_down(ss, o);
    }
    if (lane == 0) {
        float mu = s / (float)DM;
        float var = ss / (float)DM - mu * mu;
        stats[r * 2] = mu;
        stats[r * 2 + 1] = rsqrtf(var + 1e-5f);
    }
}

// ---------------- normalized mean over sequence (bf16 x input) ----------------
__global__ __launch_bounds__(256) void ln_mean_kernel(const short* __restrict__ xh,
                                                      const float* __restrict__ stats,
                                                      const float* __restrict__ nw,
                                                      const float* __restrict__ nb,
                                                      float* __restrict__ out) {
    int idx = blockIdx.x * 256 + threadIdx.x;
    if (idx >= BB * DM) return;
    int c = idx % DM;
    int b = idx / DM;
    float acc = 0.f;
    for (int l = 0; l < NP; l++) {
        size_t r = (size_t)b * NP + l;
        float v = bf2f((unsigned short)xh[r * DM + c]);
        acc += (v - stats[r * 2]) * stats[r * 2 + 1];
    }
    out[idx] = acc * (1.f / (float)NP) * nw[c] + nb[c];
}

extern "C" void kernel_launch(void* const* d_in, const int* in_sizes, int n_in,
                              void* d_out, int out_size, void* d_ws, size_t ws_size,
                              hipStream_t stream) {
    const float* img     = (const float*)d_in[0];
    const float* patch_w = (const float*)d_in[1];
    const float* patch_b = (const float*)d_in[2];
    const float* in_w    = (const float*)d_in[3];
    const float* conv_w  = (const float*)d_in[4];
    const float* conv_b  = (const float*)d_in[5];
    const float* xpw     = (const float*)d_in[6];
    const float* dtw     = (const float*)d_in[7];
    const float* dtb     = (const float*)d_in[8];
    const float* A_log   = (const float*)d_in[9];
    const float* Dv      = (const float*)d_in[10];
    const float* outw    = (const float*)d_in[11];
    const float* norm_w  = (const float*)d_in[12];
    const float* norm_b  = (const float*)d_in[13];
    float* out = (float*)d_out;

    float* ws = (float*)d_ws;
    const size_t R = RTOT;
    const size_t PLX = R * DM;                 // x bf16 plane: 2,408,448 shorts (region sized PLX fu)
    const size_t PLY = R * DINNER;             // y2/xc bf16 plane: 4,816,896 shorts
    const size_t SCN = (size_t)BB * CHUNKS * DINNER * DSTATE;   // 5,505,024 fu
    float* xA      = ws;                       // x bf16 (uses half the region)
    float* xB      = xA + PLX;
    float* xz      = xB + PLX;                 // R*768 fp32 (layers) / bf16 im2col (patch)
    float* xc      = xz + R * 768;             // R*384 fp32
    float* proj    = xc + R * DINNER;          // R*44 fp32
    float* scratch = proj + R * 44;            // shared region
    float* hEnd    = scratch;                  // SCN fu
    float* prodDA  = hEnd + SCN;               // SCN fu (becomes hInit)
    float* wpkA    = scratch + 2 * SCN;        // 147,456 fu (in_w / patch_w / xpw bf16)
    float* wpkB    = wpkA + 147456;            // 73,728 fu (outw bf16)
    float* stats   = wpkB + 73728;             // R*2

    short* y2h = (short*)scratch;              // y2 bf16 (dead hEnd region, PLY shorts)
    float* pkparts = prodDA;                   // out_proj SK2 partials (dead hInit region)
    short* xcpkH = (short*)(scratch + 2 * SCN) - PLY;   // xc bf16, tail of prodDA region (dead before scanA)

    // patch embed: pack patch_w + bf16 im2col + SK4 GEMM + reduce(+bias) -> bf16 x
    {
        short* wh = (short*)wpkA;
        pack_w_kernel<<<dim3((DM * 768 / 4 + 255) / 256), 256, 0, stream>>>(
            patch_w, wh, DM * 768);
        short* colH = (short*)xz;
        size_t n = R * 768;
        im2col_pack_kernel<<<dim3((unsigned)((n + 255) / 256)), 256, 0, stream>>>(img, colH);
        gemm_pk_kernel<64><<<dim3(3, RTOT / 128, 4), 256, 0, stream>>>(
            colH, wh, scratch, nullptr, RTOT, DM, 768, 192);
        long MN = (long)RTOT * DM;
        reduce_kernel<<<dim3((unsigned)((MN / 4 + 255) / 256)), 256, 0, stream>>>(
            scratch, nullptr, (short*)xA, patch_b, MN, DM, 4);
    }

    float* xin = xA;
    float* xout = xB;
    for (int layer = 0; layer < DEPTH; layer++) {
        const float* in_w_l  = in_w + (size_t)layer * 2 * DINNER * DM;
        const float* conv_wl = conv_w + (size_t)layer * DINNER * DCONV;
        const float* conv_bl = conv_b + (size_t)layer * DINNER;
        const float* xpw_l   = xpw + (size_t)layer * (DTR + 2 * DSTATE) * DINNER;
        const float* dtw_l   = dtw + (size_t)layer * DINNER * DTR;
        const float* dtb_l   = dtb + (size_t)layer * DINNER;
        const float* Alog_l  = A_log + (size_t)layer * DINNER * DSTATE;
        const float* Dv_l    = Dv + (size_t)layer * DINNER;
        const float* outw_l  = outw + (size_t)layer * DM * DINNER;

        short* xinH = (short*)xin;
        short* xoutH = (short*)xout;

        // pack in_w, then xz = x @ in_w^T (M=12544, N=768, K=192), direct fp32 out
        {
            short* wh = (short*)wpkA;
            pack_w_kernel<<<dim3((2 * DINNER * DM / 4 + 255) / 256), 256, 0, stream>>>(
                in_w_l, wh, 2 * DINNER * DM);
            gemm_pk_kernel<128><<<dim3(768 / 128, RTOT / 128, 1), 256, 0, stream>>>(
                xinH, wh, xz, nullptr, RTOT, 2 * DINNER, DM, DM);
        }
        // xc = silu(causal depthwise conv(xs)); also emits bf16 xc
        {
            size_t n = R * DINNER;
            conv_silu_kernel<<<dim3((unsigned)((n + 255) / 256)), 256, 0, stream>>>(
                xz, conv_wl, conv_bl, xc, xcpkH);
        }
        // pack xpw, then proj = xc @ xpw^T (N=44, K=384) SK=4, Kc=96
        {
            short* wh = (short*)wpkA;           // in_w plane dead now
            pack_w_kernel<<<dim3((44 * DINNER / 4 + 255) / 256), 256, 0, stream>>>(
                xpw_l, wh, 44 * DINNER);
            gemm_pk_kernel<64><<<dim3(1, RTOT / 128, 4), 256, 0, stream>>>(
                xcpkH, wh, scratch, nullptr, RTOT, DTR + 2 * DSTATE, DINNER, 96);
            long MN = (long)RTOT * 44;
            reduce_kernel<<<dim3((unsigned)((MN / 4 + 255) / 256)), 256, 0, stream>>>(
                scratch, proj, nullptr, nullptr, MN, 44, 4);
        }
        // dt = softplus(...) -> xz xs-half
        dt_kernel<<<dim3((RTOT * DINNER + 255) / 256), 256, 0, stream>>>(
            proj, dtw_l, dtb_l, xz);
        // chunked scan; scanC emits y2 bf16 into dead hEnd region
        scanA_kernel<<<dim3(3, CHUNKS, BB), 128, 0, stream>>>(
            xc, proj, xz, Alog_l, hEnd, prodDA);
        scanB_kernel<<<dim3((BB * DINNER * DSTATE + 255) / 256), 256, 0, stream>>>(
            hEnd, prodDA);
        scanC_kernel<<<dim3(3, CHUNKS, BB), 128, 0, stream>>>(
            xc, proj, prodDA, Alog_l, Dv_l, xz, y2h);
        // pack outw, then x_next = y2 @ outw^T (N=192, K=384) SK=2, reduce -> bf16 xout
        {
            short* wh = (short*)wpkB;
            pack_w_kernel<<<dim3((DM * DINNER / 4 + 255) / 256), 256, 0, stream>>>(
                outw_l, wh, DM * DINNER);
            gemm_pk_kernel<64><<<dim3(DM / 64, RTOT / 128, 2), 256, 0, stream>>>(
                y2h, wh, pkparts, nullptr, RTOT, DM, DINNER, 192);
            long MN = (long)RTOT * DM;
            reduce_kernel<<<dim3((unsigned)((MN / 4 + 255) / 256)), 256, 0, stream>>>(
                pkparts, nullptr, xoutH, nullptr, MN, DM, 2);
        }

        float* t = xin; xin = xout; xout = t;
    }

    // final layernorm + mean over sequence (bf16 x)
    short* xfH = (short*)xin;
    ln_stats_kernel<<<dim3(RTOT / 4), 256, 0, stream>>>(xfH, stats);
    ln_mean_kernel<<<dim3((BB * DM + 255) / 256), 256, 0, stream>>>(
        xfH, stats, norm_w, norm_b, out);
}

// Round 12
// 3828.113 us; speedup vs baseline: 1.4187x; 1.0351x over previous
//
#include <hip/hip_runtime.h>
#include <hip/hip_bf16.h>
#include <math.h>

#define BB 64
#define IMG 224
#define PP 16
#define CIN 3
#define DM 192
#define DEPTH 24
#define DSTATE 16
#define DINNER 384
#define DTR 12
#define DCONV 4
#define NP 196              // (224/16)^2
#define RTOT (BB * NP)      // 12544 rows
#define CHUNKS 14
#define LC 14               // NP / CHUNKS

typedef short bf16x8 __attribute__((ext_vector_type(8)));
typedef float f32x4 __attribute__((ext_vector_type(4)));

__device__ inline unsigned short f2bf_rne(float f) {
    unsigned u = __float_as_uint(f);
    unsigned r = u + 0x7fffu + ((u >> 16) & 1u);
    return (unsigned short)(r >> 16);
}
__device__ inline float bf2f(unsigned short s) {
    return __uint_as_float(((unsigned)s) << 16);
}

// ---------------- im2col for patch embed, emitting bf16 ----------------
__global__ __launch_bounds__(256) void im2col_pack_kernel(const float* __restrict__ img,
                                                          short* __restrict__ colH) {
    size_t idx = (size_t)blockIdx.x * 256 + threadIdx.x;
    if (idx >= (size_t)RTOT * 768) return;
    int t = (int)(idx % 768);
    size_t r = idx / 768;
    int l = (int)(r % NP);
    int b = (int)(r / NP);
    int ph = l / 14, pw = l % 14;
    int ci = t / 256, rem = t % 256;
    int i = rem / 16, j = rem % 16;
    float v = img[(((size_t)b * CIN + ci) * IMG + ph * 16 + i) * IMG + pw * 16 + j];
    colH[idx] = (short)f2bf_rne(v);
}

// ---------------- weight pack: fp32[NE] -> bf16 ----------------
__global__ __launch_bounds__(256) void pack_w_kernel(const float* __restrict__ W,
                                                     short* __restrict__ Wh, int NE) {
    int i = blockIdx.x * 256 + threadIdx.x;
    if (i * 4 >= NE) return;
    float4 v = *(const float4*)&W[i * 4];
    short4 h;
    h.x = (short)f2bf_rne(v.x);
    h.y = (short)f2bf_rne(v.y);
    h.z = (short)f2bf_rne(v.z);
    h.w = (short)f2bf_rne(v.w);
    *(short4*)&Wh[i * 4] = h;
}

// ---------------- single-plane bf16 MFMA GEMM: C[M,N] = A[M,K] * B[N,K]^T ----------------
// A,B pre-packed bf16, row stride K shorts. fp32 accumulate, 16x16x32 MFMA.
// BM=128, BK=32, 256 threads = 4 waves (2x2), wave tile 64 x BN/2.
// blockIdx.z = split-K slice (length Kc). gridDim.z==1: direct write, to bf16
// CBf if non-null else fp32 C (+bias); else partial z at C + z*M*N.
// Needs M%128==0, Kc%32==0; B rows masked vs N.
template<int BN>
__global__ __launch_bounds__(256) void gemm_pk_kernel(const short* __restrict__ Ah,
                                                      const short* __restrict__ Bh,
                                                      float* __restrict__ C,
                                                      short* __restrict__ CBf,
                                                      const float* __restrict__ bias,
                                                      int M, int N, int K, int Kc) {
    constexpr int BM = 128, BK = 32;
    constexpr int LDSS = BK + 8;                // 40 shorts = 80 B row stride
    constexpr int NF = BN / 32;                 // n-frags per wave
    constexpr int A8 = 2;                       // short8 loads/thread (A)
    constexpr int B8 = BN / 64;                 // short8 loads/thread (B)
    __shared__ short AsH[BM * LDSS];
    __shared__ short BsH[BN * LDSS];

    const int tid = threadIdx.x;
    const int lane = tid & 63;
    const int wid = tid >> 6;
    const int wr = wid >> 1, wc = wid & 1;      // 2x2 wave grid
    const int row0 = blockIdx.y * BM, col0 = blockIdx.x * BN;
    const int kbase = blockIdx.z * Kc;
    const bf16x8 ZV = {0, 0, 0, 0, 0, 0, 0, 0};

    bf16x8 aPh[A8], bPh[B8];
    f32x4 acc[4][NF] = {};

    auto loadG = [&](int k0) {
#pragma unroll
        for (int i = 0; i < A8; i++) {
            int lin = tid + i * 256;
            int r = lin >> 2, cg = (lin & 3) * 8;
            aPh[i] = *(const bf16x8*)&Ah[(size_t)(row0 + r) * K + k0 + cg];
        }
#pragma unroll
        for (int i = 0; i < B8; i++) {
            int lin = tid + i * 256;
            int r = lin >> 2, cg = (lin & 3) * 8;
            int n = col0 + r;
            bPh[i] = (n < N) ? *(const bf16x8*)&Bh[(size_t)n * K + k0 + cg] : ZV;
        }
    };
    auto storeLDS = [&]() {
#pragma unroll
        for (int i = 0; i < A8; i++) {
            int lin = tid + i * 256;
            int r = lin >> 2, cg = (lin & 3) * 8;
            *(bf16x8*)&AsH[r * LDSS + cg] = aPh[i];
        }
#pragma unroll
        for (int i = 0; i < B8; i++) {
            int lin = tid + i * 256;
            int r = lin >> 2, cg = (lin & 3) * 8;
            *(bf16x8*)&BsH[r * LDSS + cg] = bPh[i];
        }
    };

    loadG(kbase);
    storeLDS();
    __syncthreads();
    for (int k0 = kbase + BK;; k0 += BK) {
        const bool has_next = (k0 < kbase + Kc);
        if (has_next) loadG(k0);                // next-tile loads in flight
        {
            const int fr = lane & 15;           // row within 16-frag
            const int kg = (lane >> 4) * 8;     // k offset within BK=32
            bf16x8 aH[4], bH[NF];
#pragma unroll
            for (int i = 0; i < 4; i++)
                aH[i] = *(const bf16x8*)&AsH[(wr * 64 + i * 16 + fr) * LDSS + kg];
#pragma unroll
            for (int j = 0; j < NF; j++)
                bH[j] = *(const bf16x8*)&BsH[(wc * (BN / 2) + j * 16 + fr) * LDSS + kg];
#pragma unroll
            for (int i = 0; i < 4; i++)
#pragma unroll
                for (int j = 0; j < NF; j++)
                    acc[i][j] = __builtin_amdgcn_mfma_f32_16x16x32_bf16(aH[i], bH[j], acc[i][j], 0, 0, 0);
        }
        if (!has_next) break;
        __syncthreads();
        storeLDS();
        __syncthreads();
    }

    const bool direct = (gridDim.z == 1);
    float* Cout = C + (size_t)blockIdx.z * M * N;
    const int crow = (lane >> 4) * 4;
    const int ccol = lane & 15;
#pragma unroll
    for (int i = 0; i < 4; i++)
#pragma unroll
        for (int j = 0; j < NF; j++) {
            int gn = col0 + wc * (BN / 2) + j * 16 + ccol;
            if (gn >= N) continue;
            int gm0 = row0 + wr * 64 + i * 16 + crow;
            float bv = (direct && bias) ? bias[gn] : 0.f;
            if (direct && CBf) {
#pragma unroll
                for (int reg = 0; reg < 4; reg++)
                    CBf[(size_t)(gm0 + reg) * N + gn] = (short)f2bf_rne(acc[i][j][reg] + bv);
            } else {
#pragma unroll
                for (int reg = 0; reg < 4; reg++)
                    Cout[(size_t)(gm0 + reg) * N + gn] = acc[i][j][reg] + bv;
            }
        }
}

// ---------------- split-K reduce: sum parts (+bias); fp32 OR packed bf16 output ----------------
__global__ __launch_bounds__(256) void reduce_kernel(const float* __restrict__ parts,
                                                     float* __restrict__ Cf,
                                                     short* __restrict__ outH,
                                                     const float* __restrict__ bias,
                                                     long MN, int N, int SK) {
    long i = (long)blockIdx.x * 256 + threadIdx.x;      // float4 index
    if (i * 4 >= MN) return;
    float4 acc = *(const float4*)&parts[i * 4];
    for (int z = 1; z < SK; z++) {
        float4 v = *(const float4*)&parts[(size_t)z * MN + i * 4];
        acc.x += v.x; acc.y += v.y; acc.z += v.z; acc.w += v.w;
    }
    if (bias) {
        int col = (int)((i * 4) % N);
        float4 bv = *(const float4*)&bias[col];
        acc.x += bv.x; acc.y += bv.y; acc.z += bv.z; acc.w += bv.w;
    }
    if (outH) {
        short4 h;
        h.x = (short)f2bf_rne(acc.x);
        h.y = (short)f2bf_rne(acc.y);
        h.z = (short)f2bf_rne(acc.z);
        h.w = (short)f2bf_rne(acc.w);
        *(short4*)&outH[i * 4] = h;
    } else {
        *(float4*)&Cf[i * 4] = acc;
    }
}

// ---------------- causal depthwise conv (DCONV=4) + SiLU; bf16 in, fp32 + bf16 out ----------------
__global__ __launch_bounds__(256) void conv_silu_kernel(const short* __restrict__ xzBf,
                                                        const float* __restrict__ cw,
                                                        const float* __restrict__ cb,
                                                        float* __restrict__ xc,
                                                        short* __restrict__ xcH) {
    size_t idx = (size_t)blockIdx.x * 256 + threadIdx.x;
    if (idx >= (size_t)RTOT * DINNER) return;
    int e = (int)(idx % DINNER);
    size_t r = idx / DINNER;
    int l = (int)(r % NP);
    size_t b = r / NP;
    const float* w = cw + (size_t)e * DCONV;
    float acc = cb[e];
#pragma unroll
    for (int k = 0; k < DCONV; k++) {
        int ls = l + k - (DCONV - 1);
        if (ls >= 0) acc += bf2f((unsigned short)xzBf[(b * NP + ls) * 768 + e]) * w[k];
    }
    float val = acc / (1.f + __expf(-acc));   // silu (fast exp)
    xc[idx] = val;
    xcH[idx] = (short)f2bf_rne(val);
}

// ---------------- dt projection + softplus -> fp32 dtbuf ----------------
__global__ __launch_bounds__(256) void dt_kernel(const float* __restrict__ proj,
                                                 const float* __restrict__ dtw,
                                                 const float* __restrict__ dtb,
                                                 float* __restrict__ dt) {
    int idx = blockIdx.x * 256 + threadIdx.x;
    if (idx >= RTOT * DINNER) return;
    int d = idx % DINNER;
    size_t r = (size_t)idx / DINNER;
    const float* pr = proj + r * 44;
    const float* w = dtw + (size_t)d * DTR;
    float acc = dtb[d];
#pragma unroll
    for (int k = 0; k < DTR; k++) acc += pr[k] * w[k];
    dt[idx] = (acc > 20.f) ? acc : __logf(1.f + __expf(acc));
}

// ---------------- chunked selective scan: lane owns (b,d), 16 states in regs ----------------
__global__ __launch_bounds__(128) void scanA_kernel(const float* __restrict__ xc,
                                                    const float* __restrict__ proj,
                                                    const float* __restrict__ dt,
                                                    const float* __restrict__ A_log,
                                                    float* __restrict__ hEnd,
                                                    float* __restrict__ prodDA) {
    int d = blockIdx.x * 128 + threadIdx.x;       // grid.x = 3
    int c = blockIdx.y, b = blockIdx.z;
    float a[DSTATE], h[DSTATE], p[DSTATE];
#pragma unroll
    for (int s = 0; s < DSTATE; s++) {
        a[s] = -expf(A_log[(size_t)d * DSTATE + s]);   // precise (once per lane)
        h[s] = 0.f;
        p[s] = 1.f;
    }
    size_t rbase = (size_t)b * NP + (size_t)c * LC;
    for (int l = 0; l < LC; l++) {
        size_t r = rbase + l;
        float dtv = dt[r * DINNER + d];
        float du = dtv * xc[r * DINNER + d];
        const float* pb = proj + r * 44 + DTR;    // wave-uniform
        float Bv[DSTATE];
        *(float4*)&Bv[0]  = *(const float4*)&pb[0];
        *(float4*)&Bv[4]  = *(const float4*)&pb[4];
        *(float4*)&Bv[8]  = *(const float4*)&pb[8];
        *(float4*)&Bv[12] = *(const float4*)&pb[12];
#pragma unroll
        for (int s = 0; s < DSTATE; s++) {
            float dA = __expf(dtv * a[s]);        // fast exp (hot loop)
            h[s] = h[s] * dA + du * Bv[s];
            p[s] *= dA;
        }
    }
    float* he = hEnd   + (((size_t)b * CHUNKS + c) * DINNER + d) * DSTATE;
    float* pd = prodDA + (((size_t)b * CHUNKS + c) * DINNER + d) * DSTATE;
#pragma unroll
    for (int g = 0; g < 4; g++) {
        *(float4*)&he[g * 4] = *(float4*)&h[g * 4];
        *(float4*)&pd[g * 4] = *(float4*)&p[g * 4];
    }
}

__global__ __launch_bounds__(256) void scanB_kernel(const float* __restrict__ hEnd,
                                                    float* __restrict__ prodDA) {
    int idx = blockIdx.x * 256 + threadIdx.x;
    if (idx >= BB * DINNER * DSTATE) return;
    int b = idx / (DINNER * DSTATE);
    int rem = idx % (DINNER * DSTATE);
    float run = 0.f;
    for (int c = 0; c < CHUNKS; c++) {
        size_t off = ((size_t)b * CHUNKS + c) * (DINNER * DSTATE) + rem;
        float p = prodDA[off];
        float e = hEnd[off];
        prodDA[off] = run;          // hInit for chunk c
        run = run * p + e;
    }
}

// Pass C: rerun from hInit; fused (y+u*D)*silu(z) [z from bf16 xz]; emits y2 bf16.
__global__ __launch_bounds__(128) void scanC_kernel(const float* __restrict__ xc,
                                                    const float* __restrict__ proj,
                                                    const float* __restrict__ dt,
                                                    const float* __restrict__ hInit,
                                                    const float* __restrict__ A_log,
                                                    const float* __restrict__ Dv,
                                                    const short* __restrict__ xzBf,
                                                    short* __restrict__ yh) {
    int d = blockIdx.x * 128 + threadIdx.x;       // grid.x = 3
    int c = blockIdx.y, b = blockIdx.z;
    float a[DSTATE], h[DSTATE];
#pragma unroll
    for (int s = 0; s < DSTATE; s++)
        a[s] = -expf(A_log[(size_t)d * DSTATE + s]);   // precise (once per lane)
    const float* hi = hInit + (((size_t)b * CHUNKS + c) * DINNER + d) * DSTATE;
#pragma unroll
    for (int g = 0; g < 4; g++)
        *(float4*)&h[g * 4] = *(const float4*)&hi[g * 4];
    float Dd = Dv[d];
    size_t rbase = (size_t)b * NP + (size_t)c * LC;
    for (int l = 0; l < LC; l++) {
        size_t r = rbase + l;
        float dtv = dt[r * DINNER + d];
        float u = xc[r * DINNER + d];
        float du = dtv * u;
        const float* pb = proj + r * 44 + DTR;              // wave-uniform
        const float* pc = proj + r * 44 + DTR + DSTATE;
        float Bv[DSTATE], Cv[DSTATE];
        *(float4*)&Bv[0]  = *(const float4*)&pb[0];
        *(float4*)&Bv[4]  = *(const float4*)&pb[4];
        *(float4*)&Bv[8]  = *(const float4*)&pb[8];
        *(float4*)&Bv[12] = *(const float4*)&pb[12];
        *(float4*)&Cv[0]  = *(const float4*)&pc[0];
        *(float4*)&Cv[4]  = *(const float4*)&pc[4];
        *(float4*)&Cv[8]  = *(const float4*)&pc[8];
        *(float4*)&Cv[12] = *(const float4*)&pc[12];
        float y = 0.f;
#pragma unroll
        for (int s = 0; s < DSTATE; s++) {
            float dA = __expf(dtv * a[s]);        // fast exp (hot loop)
            h[s] = h[s] * dA + du * Bv[s];
            y = fmaf(h[s], Cv[s], y);
        }
        float z = bf2f((unsigned short)xzBf[r * 768 + DINNER + d]);
        float val = (y + u * Dd) * (z / (1.f + __expf(-z)));
        yh[r * DINNER + d] = (short)f2bf_rne(val);
    }
}

// ---------------- final layernorm: per-row stats (bf16 x input) ----------------
__global__ __launch_bounds__(256) void ln_stats_kernel(const short* __restrict__ xh,
                                                       float* __restrict__ stats) {
    int r = blockIdx.x * 4 + (threadIdx.x >> 6);
    int lane = threadIdx.x & 63;
    if (r >= RTOT) return;
    float s = 0.f, ss = 0.f;
    for (int c = lane; c < DM; c += 64) {
        float v = bf2f((unsigned short)xh[(size_t)r * DM + c]);
        s += v;
        ss += v * v;
    }
#pragma unroll
    for (int o = 32; o > 0; o >>= 1) {
        s += __shfl_down(s, o);
        ss += __shfl_down(ss, o);
    }
    if (lane == 0) {
        float mu = s / (float)DM;
        float var = ss / (float)DM - mu * mu;
        stats[r * 2] = mu;
        stats[r * 2 + 1] = rsqrtf(var + 1e-5f);
    }
}

// ---------------- normalized mean over sequence (bf16 x input) ----------------
__global__ __launch_bounds__(256) void ln_mean_kernel(const short* __restrict__ xh,
                                                      const float* __restrict__ stats,
                                                      const float* __restrict__ nw,
                                                      const float* __restrict__ nb,
                                                      float* __restrict__ out) {
    int idx = blockIdx.x * 256 + threadIdx.x;
    if (idx >= BB * DM) return;
    int c = idx % DM;
    int b = idx / DM;
    float acc = 0.f;
    for (int l = 0; l < NP; l++) {
        size_t r = (size_t)b * NP + l;
        float v = bf2f((unsigned short)xh[r * DM + c]);
        acc += (v - stats[r * 2]) * stats[r * 2 + 1];
    }
    out[idx] = acc * (1.f / (float)NP) * nw[c] + nb[c];
}

extern "C" void kernel_launch(void* const* d_in, const int* in_sizes, int n_in,
                              void* d_out, int out_size, void* d_ws, size_t ws_size,
                              hipStream_t stream) {
    const float* img     = (const float*)d_in[0];
    const float* patch_w = (const float*)d_in[1];
    const float* patch_b = (const float*)d_in[2];
    const float* in_w    = (const float*)d_in[3];
    const float* conv_w  = (const float*)d_in[4];
    const float* conv_b  = (const float*)d_in[5];
    const float* xpw     = (const float*)d_in[6];
    const float* dtw     = (const float*)d_in[7];
    const float* dtb     = (const float*)d_in[8];
    const float* A_log   = (const float*)d_in[9];
    const float* Dv      = (const float*)d_in[10];
    const float* outw    = (const float*)d_in[11];
    const float* norm_w  = (const float*)d_in[12];
    const float* norm_b  = (const float*)d_in[13];
    float* out = (float*)d_out;

    float* ws = (float*)d_ws;
    const size_t R = RTOT;
    const size_t PLY = R * DINNER;             // 4,816,896 shorts (y2 / xc bf16 plane)
    const size_t SCN = (size_t)BB * CHUNKS * DINNER * DSTATE;   // 5,505,024 fu

    float* xA      = ws;                       // x bf16: R*DM shorts = 1,204,224 fu
    float* xB      = xA + R * DM / 2;
    float* xzB     = xB + R * DM / 2;          // xz bf16: R*768 shorts = 2,408,448 fu (also im2col col)
    float* xc      = xzB + R * 768 / 2;        // R*384 fp32
    float* dtbuf   = xc + R * DINNER;          // R*384 fp32
    float* proj    = dtbuf + R * DINNER;       // R*44 fp32
    float* scratch = proj + R * 44;            // 2*SCN shared (partials / hEnd+prodDA / y2 / xcpk)
    float* wAll    = scratch + 2 * SCN;        // packed weights (shorts)
    float* stats   = wAll + 2930688;           // R*2

    // packed weight layout (shorts within wAll)
    short* wPatch = (short*)wAll;                          // 192*768        = 147,456
    short* wIn    = wPatch + (size_t)DM * 768;             // 24*768*192     = 3,538,944
    short* wXp    = wIn + (size_t)DEPTH * 2 * DINNER * DM; // 24*44*384      = 405,504
    short* wOut   = wXp + (size_t)DEPTH * 44 * DINNER;     // 24*192*384     = 1,769,472

    short* y2h = (short*)scratch;              // y2 bf16 (dead hEnd region)
    float* pkparts = scratch + SCN;            // out_proj SK2 partials (dead hInit region)
    short* xcpkH = (short*)(scratch + 2 * SCN) - PLY;   // xc bf16, tail of prodDA region

    // ---- pre-pack ALL weights once (4 launches, off the per-layer critical path) ----
    pack_w_kernel<<<dim3((DM * 768 / 4 + 255) / 256), 256, 0, stream>>>(
        patch_w, wPatch, DM * 768);
    pack_w_kernel<<<dim3((DEPTH * 2 * DINNER * DM / 4 + 255) / 256), 256, 0, stream>>>(
        in_w, wIn, DEPTH * 2 * DINNER * DM);
    pack_w_kernel<<<dim3((DEPTH * 44 * DINNER / 4 + 255) / 256), 256, 0, stream>>>(
        xpw, wXp, DEPTH * 44 * DINNER);
    pack_w_kernel<<<dim3((DEPTH * DM * DINNER / 4 + 255) / 256), 256, 0, stream>>>(
        outw, wOut, DEPTH * DM * DINNER);

    // ---- patch embed: bf16 im2col + SK4 GEMM + reduce(+bias) -> bf16 x ----
    {
        short* colH = (short*)xzB;
        size_t n = R * 768;
        im2col_pack_kernel<<<dim3((unsigned)((n + 255) / 256)), 256, 0, stream>>>(img, colH);
        gemm_pk_kernel<64><<<dim3(3, RTOT / 128, 4), 256, 0, stream>>>(
            colH, wPatch, scratch, nullptr, nullptr, RTOT, DM, 768, 192);
        long MN = (long)RTOT * DM;
        reduce_kernel<<<dim3((unsigned)((MN / 4 + 255) / 256)), 256, 0, stream>>>(
            scratch, nullptr, (short*)xA, patch_b, MN, DM, 4);
    }

    float* xin = xA;
    float* xout = xB;
    for (int layer = 0; layer < DEPTH; layer++) {
        const float* conv_wl = conv_w + (size_t)layer * DINNER * DCONV;
        const float* conv_bl = conv_b + (size_t)layer * DINNER;
        const float* dtw_l   = dtw + (size_t)layer * DINNER * DTR;
        const float* dtb_l   = dtb + (size_t)layer * DINNER;
        const float* Alog_l  = A_log + (size_t)layer * DINNER * DSTATE;
        const float* Dv_l    = Dv + (size_t)layer * DINNER;
        short* wIn_l  = wIn + (size_t)layer * 2 * DINNER * DM;
        short* wXp_l  = wXp + (size_t)layer * 44 * DINNER;
        short* wOut_l = wOut + (size_t)layer * DM * DINNER;

        short* xinH = (short*)xin;
        short* xoutH = (short*)xout;
        short* xzH = (short*)xzB;

        // xz(bf16) = x @ in_w^T   (M=12544, N=768, K=192), direct bf16 out
        gemm_pk_kernel<128><<<dim3(768 / 128, RTOT / 128, 1), 256, 0, stream>>>(
            xinH, wIn_l, nullptr, xzH, nullptr, RTOT, 2 * DINNER, DM, DM);
        // xc = silu(causal depthwise conv(xs bf16)); emits fp32 + bf16
        {
            size_t n = R * DINNER;
            conv_silu_kernel<<<dim3((unsigned)((n + 255) / 256)), 256, 0, stream>>>(
                xzH, conv_wl, conv_bl, xc, xcpkH);
        }
        // proj = xc @ xpw^T (N=44, K=384) SK=4, Kc=96 + reduce
        gemm_pk_kernel<64><<<dim3(1, RTOT / 128, 4), 256, 0, stream>>>(
            xcpkH, wXp_l, scratch, nullptr, nullptr, RTOT, DTR + 2 * DSTATE, DINNER, 96);
        {
            long MN = (long)RTOT * 44;
            reduce_kernel<<<dim3((unsigned)((MN / 4 + 255) / 256)), 256, 0, stream>>>(
                scratch, proj, nullptr, nullptr, MN, 44, 4);
        }
        // dt = softplus(proj[:, :12] @ dtw^T + dtb) -> fp32 dtbuf
        dt_kernel<<<dim3((RTOT * DINNER + 255) / 256), 256, 0, stream>>>(
            proj, dtw_l, dtb_l, dtbuf);
        // chunked scan; scanC emits y2 bf16 into dead hEnd region
        scanA_kernel<<<dim3(3, CHUNKS, BB), 128, 0, stream>>>(
            xc, proj, dtbuf, Alog_l, scratch, scratch + SCN);
        scanB_kernel<<<dim3((BB * DINNER * DSTATE + 255) / 256), 256, 0, stream>>>(
            scratch, scratch + SCN);
        scanC_kernel<<<dim3(3, CHUNKS, BB), 128, 0, stream>>>(
            xc, proj, dtbuf, scratch + SCN, Alog_l, Dv_l, xzH, y2h);
        // x_next = y2 @ outw^T (N=192, K=384) SK=2 + reduce -> bf16 xout
        gemm_pk_kernel<64><<<dim3(DM / 64, RTOT / 128, 2), 256, 0, stream>>>(
            y2h, wOut_l, pkparts, nullptr, nullptr, RTOT, DM, DINNER, 192);
        {
            long MN = (long)RTOT * DM;
            reduce_kernel<<<dim3((unsigned)((MN / 4 + 255) / 256)), 256, 0, stream>>>(
                pkparts, nullptr, xoutH, nullptr, MN, DM, 2);
        }

        float* t = xin; xin = xout; xout = t;
    }

    // final layernorm + mean over sequence (bf16 x)
    short* xfH = (short*)xin;
    ln_stats_kernel<<<dim3(RTOT / 4), 256, 0, stream>>>(xfH, stats);
    ln_mean_kernel<<<dim3((BB * DM + 255) / 256), 256, 0, stream>>>(
        xfH, stats, norm_w, norm_b, out);
}

// Round 13
// 3542.753 us; speedup vs baseline: 1.5330x; 1.0805x over previous
//
#include <hip/hip_runtime.h>
#include <hip/hip_bf16.h>
#include <math.h>

#define BB 64
#define IMG 224
#define PP 16
#define CIN 3
#define DM 192
#define DEPTH 24
#define DSTATE 16
#define DINNER 384
#define DTR 12
#define DCONV 4
#define NP 196              // (224/16)^2
#define RTOT (BB * NP)      // 12544 rows
#define CHUNKS 14
#define LC 14               // NP / CHUNKS
#define NCMB (2 * DSTATE + DINNER)   // 416 = B,C (32) + dt (384)

typedef short bf16x8 __attribute__((ext_vector_type(8)));
typedef float f32x4 __attribute__((ext_vector_type(4)));

__device__ inline unsigned short f2bf_rne(float f) {
    unsigned u = __float_as_uint(f);
    unsigned r = u + 0x7fffu + ((u >> 16) & 1u);
    return (unsigned short)(r >> 16);
}
__device__ inline float bf2f(unsigned short s) {
    return __uint_as_float(((unsigned)s) << 16);
}

// ---------------- im2col for patch embed, emitting bf16 ----------------
__global__ __launch_bounds__(256) void im2col_pack_kernel(const float* __restrict__ img,
                                                          short* __restrict__ colH) {
    size_t idx = (size_t)blockIdx.x * 256 + threadIdx.x;
    if (idx >= (size_t)RTOT * 768) return;
    int t = (int)(idx % 768);
    size_t r = idx / 768;
    int l = (int)(r % NP);
    int b = (int)(r / NP);
    int ph = l / 14, pw = l % 14;
    int ci = t / 256, rem = t % 256;
    int i = rem / 16, j = rem % 16;
    float v = img[(((size_t)b * CIN + ci) * IMG + ph * 16 + i) * IMG + pw * 16 + j];
    colH[idx] = (short)f2bf_rne(v);
}

// ---------------- weight pack: fp32[NE] -> bf16 ----------------
__global__ __launch_bounds__(256) void pack_w_kernel(const float* __restrict__ W,
                                                     short* __restrict__ Wh, int NE) {
    int i = blockIdx.x * 256 + threadIdx.x;
    if (i * 4 >= NE) return;
    float4 v = *(const float4*)&W[i * 4];
    short4 h;
    h.x = (short)f2bf_rne(v.x);
    h.y = (short)f2bf_rne(v.y);
    h.z = (short)f2bf_rne(v.z);
    h.w = (short)f2bf_rne(v.w);
    *(short4*)&Wh[i * 4] = h;
}

// ---------------- combined xproj weight: [DEPTH][416][384] bf16 ----------------
// rows 0..31  = xpw rows 12..43 (B then C)
// rows 32..415 = dt-fold: W[d,k] = sum_j dtw[d,j] * xpw[j,k]
__global__ __launch_bounds__(256) void wcmb_kernel(const float* __restrict__ xpw,
                                                   const float* __restrict__ dtw,
                                                   short* __restrict__ wCmb) {
    int idx = blockIdx.x * 256 + threadIdx.x;
    if (idx >= DEPTH * NCMB * DINNER) return;
    int layer = idx / (NCMB * DINNER);
    int rem = idx % (NCMB * DINNER);
    int n = rem / DINNER;
    int k = rem % DINNER;
    const float* xp = xpw + (size_t)layer * 44 * DINNER;
    float v;
    if (n < 32) {
        v = xp[(DTR + n) * DINNER + k];
    } else {
        int d = n - 32;
        const float* w = dtw + ((size_t)layer * DINNER + d) * DTR;
        v = 0.f;
#pragma unroll
        for (int j = 0; j < DTR; j++) v += w[j] * xp[j * DINNER + k];
    }
    wCmb[idx] = (short)f2bf_rne(v);
}

// ---------------- single-plane bf16 MFMA GEMM: C[M,N] = A[M,K] * B[N,K]^T ----------------
// BM=128, BK=32, 256 threads = 4 waves (2x2), wave tile 64 x BN/2, fp32 acc.
// gridDim.z==1: direct write to bf16 CBf if non-null else fp32 C (+bias);
// else partial z at C + z*M*N. Needs M%128==0, Kc%32==0; B rows masked vs N.
template<int BN>
__global__ __launch_bounds__(256) void gemm_pk_kernel(const short* __restrict__ Ah,
                                                      const short* __restrict__ Bh,
                                                      float* __restrict__ C,
                                                      short* __restrict__ CBf,
                                                      const float* __restrict__ bias,
                                                      int M, int N, int K, int Kc) {
    constexpr int BM = 128, BK = 32;
    constexpr int LDSS = BK + 8;
    constexpr int NF = BN / 32;
    constexpr int A8 = 2;
    constexpr int B8 = BN / 64;
    __shared__ short AsH[BM * LDSS];
    __shared__ short BsH[BN * LDSS];

    const int tid = threadIdx.x;
    const int lane = tid & 63;
    const int wid = tid >> 6;
    const int wr = wid >> 1, wc = wid & 1;
    const int row0 = blockIdx.y * BM, col0 = blockIdx.x * BN;
    const int kbase = blockIdx.z * Kc;
    const bf16x8 ZV = {0, 0, 0, 0, 0, 0, 0, 0};

    bf16x8 aPh[A8], bPh[B8];
    f32x4 acc[4][NF] = {};

    auto loadG = [&](int k0) {
#pragma unroll
        for (int i = 0; i < A8; i++) {
            int lin = tid + i * 256;
            int r = lin >> 2, cg = (lin & 3) * 8;
            aPh[i] = *(const bf16x8*)&Ah[(size_t)(row0 + r) * K + k0 + cg];
        }
#pragma unroll
        for (int i = 0; i < B8; i++) {
            int lin = tid + i * 256;
            int r = lin >> 2, cg = (lin & 3) * 8;
            int n = col0 + r;
            bPh[i] = (n < N) ? *(const bf16x8*)&Bh[(size_t)n * K + k0 + cg] : ZV;
        }
    };
    auto storeLDS = [&]() {
#pragma unroll
        for (int i = 0; i < A8; i++) {
            int lin = tid + i * 256;
            int r = lin >> 2, cg = (lin & 3) * 8;
            *(bf16x8*)&AsH[r * LDSS + cg] = aPh[i];
        }
#pragma unroll
        for (int i = 0; i < B8; i++) {
            int lin = tid + i * 256;
            int r = lin >> 2, cg = (lin & 3) * 8;
            *(bf16x8*)&BsH[r * LDSS + cg] = bPh[i];
        }
    };

    loadG(kbase);
    storeLDS();
    __syncthreads();
    for (int k0 = kbase + BK;; k0 += BK) {
        const bool has_next = (k0 < kbase + Kc);
        if (has_next) loadG(k0);
        {
            const int fr = lane & 15;
            const int kg = (lane >> 4) * 8;
            bf16x8 aH[4], bH[NF];
#pragma unroll
            for (int i = 0; i < 4; i++)
                aH[i] = *(const bf16x8*)&AsH[(wr * 64 + i * 16 + fr) * LDSS + kg];
#pragma unroll
            for (int j = 0; j < NF; j++)
                bH[j] = *(const bf16x8*)&BsH[(wc * (BN / 2) + j * 16 + fr) * LDSS + kg];
#pragma unroll
            for (int i = 0; i < 4; i++)
#pragma unroll
                for (int j = 0; j < NF; j++)
                    acc[i][j] = __builtin_amdgcn_mfma_f32_16x16x32_bf16(aH[i], bH[j], acc[i][j], 0, 0, 0);
        }
        if (!has_next) break;
        __syncthreads();
        storeLDS();
        __syncthreads();
    }

    const bool direct = (gridDim.z == 1);
    float* Cout = C + (size_t)blockIdx.z * M * N;
    const int crow = (lane >> 4) * 4;
    const int ccol = lane & 15;
#pragma unroll
    for (int i = 0; i < 4; i++)
#pragma unroll
        for (int j = 0; j < NF; j++) {
            int gn = col0 + wc * (BN / 2) + j * 16 + ccol;
            if (gn >= N) continue;
            int gm0 = row0 + wr * 64 + i * 16 + crow;
            float bv = (direct && bias) ? bias[gn] : 0.f;
            if (direct && CBf) {
#pragma unroll
                for (int reg = 0; reg < 4; reg++)
                    CBf[(size_t)(gm0 + reg) * N + gn] = (short)f2bf_rne(acc[i][j][reg] + bv);
            } else {
#pragma unroll
                for (int reg = 0; reg < 4; reg++)
                    Cout[(size_t)(gm0 + reg) * N + gn] = acc[i][j][reg] + bv;
            }
        }
}

// ---------------- fused xproj GEMM: [B,C | dt] = xc @ wCmb^T ----------------
// N=416. cols 0..31 -> projBC fp32 (stride 32); cols 32..415 -> dt bf16 =
// softplus(acc + dtb[col-32]) (stride 384). BM=128, BN=64, BK=32, K=Kc=384.
__global__ __launch_bounds__(256) void gemm_xproj_kernel(const short* __restrict__ Ah,
                                                         const short* __restrict__ Bh,
                                                         float* __restrict__ projBC,
                                                         short* __restrict__ dtB,
                                                         const float* __restrict__ dtb,
                                                         int M, int K) {
    constexpr int BM = 128, BN = 64, BK = 32;
    constexpr int LDSS = BK + 8;
    constexpr int N = NCMB;
    __shared__ short AsH[BM * LDSS];
    __shared__ short BsH[BN * LDSS];

    const int tid = threadIdx.x;
    const int lane = tid & 63;
    const int wid = tid >> 6;
    const int wr = wid >> 1, wc = wid & 1;
    const int row0 = blockIdx.y * BM, col0 = blockIdx.x * BN;
    const bf16x8 ZV = {0, 0, 0, 0, 0, 0, 0, 0};

    bf16x8 aPh[2], bPh[1];
    f32x4 acc[4][1] = {};

    auto loadG = [&](int k0) {
#pragma unroll
        for (int i = 0; i < 2; i++) {
            int lin = tid + i * 256;
            int r = lin >> 2, cg = (lin & 3) * 8;
            aPh[i] = *(const bf16x8*)&Ah[(size_t)(row0 + r) * K + k0 + cg];
        }
        {
            int r = tid >> 2, cg = (tid & 3) * 8;
            int n = col0 + r;
            bPh[0] = (n < N) ? *(const bf16x8*)&Bh[(size_t)n * K + k0 + cg] : ZV;
        }
    };
    auto storeLDS = [&]() {
#pragma unroll
        for (int i = 0; i < 2; i++) {
            int lin = tid + i * 256;
            int r = lin >> 2, cg = (lin & 3) * 8;
            *(bf16x8*)&AsH[r * LDSS + cg] = aPh[i];
        }
        {
            int r = tid >> 2, cg = (tid & 3) * 8;
            *(bf16x8*)&BsH[r * LDSS + cg] = bPh[0];
        }
    };

    loadG(0);
    storeLDS();
    __syncthreads();
    for (int k0 = BK;; k0 += BK) {
        const bool has_next = (k0 < K);
        if (has_next) loadG(k0);
        {
            const int fr = lane & 15;
            const int kg = (lane >> 4) * 8;
            bf16x8 aH[4], bH;
#pragma unroll
            for (int i = 0; i < 4; i++)
                aH[i] = *(const bf16x8*)&AsH[(wr * 64 + i * 16 + fr) * LDSS + kg];
            bH = *(const bf16x8*)&BsH[(wc * 32 + fr) * LDSS + kg];
#pragma unroll
            for (int i = 0; i < 4; i++)
                acc[i][0] = __builtin_amdgcn_mfma_f32_16x16x32_bf16(aH[i], bH, acc[i][0], 0, 0, 0);
        }
        if (!has_next) break;
        __syncthreads();
        storeLDS();
        __syncthreads();
    }

    const int crow = (lane >> 4) * 4;
    const int ccol = lane & 15;
#pragma unroll
    for (int i = 0; i < 4; i++) {
        int gn = col0 + wc * 32 + ccol;
        if (gn >= NCMB) continue;
        int gm0 = row0 + wr * 64 + i * 16 + crow;
        if (gn < 32) {
#pragma unroll
            for (int reg = 0; reg < 4; reg++)
                projBC[(size_t)(gm0 + reg) * 32 + gn] = acc[i][0][reg];
        } else {
            int d = gn - 32;
            float bv = dtb[d];
#pragma unroll
            for (int reg = 0; reg < 4; reg++) {
                float v = acc[i][0][reg] + bv;
                v = (v > 20.f) ? v : __logf(1.f + __expf(v));   // softplus
                dtB[(size_t)(gm0 + reg) * DINNER + d] = (short)f2bf_rne(v);
            }
        }
    }
}

// ---------------- split-K reduce: sum parts (+bias); fp32 OR packed bf16 output ----------------
__global__ __launch_bounds__(256) void reduce_kernel(const float* __restrict__ parts,
                                                     float* __restrict__ Cf,
                                                     short* __restrict__ outH,
                                                     const float* __restrict__ bias,
                                                     long MN, int N, int SK) {
    long i = (long)blockIdx.x * 256 + threadIdx.x;
    if (i * 4 >= MN) return;
    float4 acc = *(const float4*)&parts[i * 4];
    for (int z = 1; z < SK; z++) {
        float4 v = *(const float4*)&parts[(size_t)z * MN + i * 4];
        acc.x += v.x; acc.y += v.y; acc.z += v.z; acc.w += v.w;
    }
    if (bias) {
        int col = (int)((i * 4) % N);
        float4 bv = *(const float4*)&bias[col];
        acc.x += bv.x; acc.y += bv.y; acc.z += bv.z; acc.w += bv.w;
    }
    if (outH) {
        short4 h;
        h.x = (short)f2bf_rne(acc.x);
        h.y = (short)f2bf_rne(acc.y);
        h.z = (short)f2bf_rne(acc.z);
        h.w = (short)f2bf_rne(acc.w);
        *(short4*)&outH[i * 4] = h;
    } else {
        *(float4*)&Cf[i * 4] = acc;
    }
}

// ---------------- causal depthwise conv (DCONV=4) + SiLU; bf16 in, bf16 out ----------------
__global__ __launch_bounds__(256) void conv_silu_kernel(const short* __restrict__ xzBf,
                                                        const float* __restrict__ cw,
                                                        const float* __restrict__ cb,
                                                        short* __restrict__ xcH) {
    size_t idx = (size_t)blockIdx.x * 256 + threadIdx.x;
    if (idx >= (size_t)RTOT * DINNER) return;
    int e = (int)(idx % DINNER);
    size_t r = idx / DINNER;
    int l = (int)(r % NP);
    size_t b = r / NP;
    const float* w = cw + (size_t)e * DCONV;
    float acc = cb[e];
#pragma unroll
    for (int k = 0; k < DCONV; k++) {
        int ls = l + k - (DCONV - 1);
        if (ls >= 0) acc += bf2f((unsigned short)xzBf[(b * NP + ls) * 768 + e]) * w[k];
    }
    float val = acc / (1.f + __expf(-acc));   // silu (fast exp)
    xcH[idx] = (short)f2bf_rne(val);
}

// ---------------- chunked selective scan: lane owns (b,d), 16 states in regs ----------------
__global__ __launch_bounds__(128) void scanA_kernel(const short* __restrict__ xcB,
                                                    const float* __restrict__ projBC,
                                                    const short* __restrict__ dtB,
                                                    const float* __restrict__ A_log,
                                                    float* __restrict__ hEnd,
                                                    float* __restrict__ prodDA) {
    int d = blockIdx.x * 128 + threadIdx.x;       // grid.x = 3
    int c = blockIdx.y, b = blockIdx.z;
    float a[DSTATE], h[DSTATE], p[DSTATE];
#pragma unroll
    for (int s = 0; s < DSTATE; s++) {
        a[s] = -expf(A_log[(size_t)d * DSTATE + s]);   // precise (once per lane)
        h[s] = 0.f;
        p[s] = 1.f;
    }
    size_t rbase = (size_t)b * NP + (size_t)c * LC;
    for (int l = 0; l < LC; l++) {
        size_t r = rbase + l;
        float dtv = bf2f((unsigned short)dtB[r * DINNER + d]);
        float du = dtv * bf2f((unsigned short)xcB[r * DINNER + d]);
        const float* pb = projBC + r * 32;        // wave-uniform
        float Bv[DSTATE];
        *(float4*)&Bv[0]  = *(const float4*)&pb[0];
        *(float4*)&Bv[4]  = *(const float4*)&pb[4];
        *(float4*)&Bv[8]  = *(const float4*)&pb[8];
        *(float4*)&Bv[12] = *(const float4*)&pb[12];
#pragma unroll
        for (int s = 0; s < DSTATE; s++) {
            float dA = __expf(dtv * a[s]);        // fast exp (hot loop)
            h[s] = h[s] * dA + du * Bv[s];
            p[s] *= dA;
        }
    }
    float* he = hEnd   + (((size_t)b * CHUNKS + c) * DINNER + d) * DSTATE;
    float* pd = prodDA + (((size_t)b * CHUNKS + c) * DINNER + d) * DSTATE;
#pragma unroll
    for (int g = 0; g < 4; g++) {
        *(float4*)&he[g * 4] = *(float4*)&h[g * 4];
        *(float4*)&pd[g * 4] = *(float4*)&p[g * 4];
    }
}

__global__ __launch_bounds__(256) void scanB_kernel(const float* __restrict__ hEnd,
                                                    float* __restrict__ prodDA) {
    int idx = blockIdx.x * 256 + threadIdx.x;
    if (idx >= BB * DINNER * DSTATE) return;
    int b = idx / (DINNER * DSTATE);
    int rem = idx % (DINNER * DSTATE);
    float run = 0.f;
    for (int c = 0; c < CHUNKS; c++) {
        size_t off = ((size_t)b * CHUNKS + c) * (DINNER * DSTATE) + rem;
        float p = prodDA[off];
        float e = hEnd[off];
        prodDA[off] = run;          // hInit for chunk c
        run = run * p + e;
    }
}

// Pass C: rerun from hInit; fused (y+u*D)*silu(z) [z from bf16 xz]; emits y2 bf16.
__global__ __launch_bounds__(128) void scanC_kernel(const short* __restrict__ xcB,
                                                    const float* __restrict__ projBC,
                                                    const short* __restrict__ dtB,
                                                    const float* __restrict__ hInit,
                                                    const float* __restrict__ A_log,
                                                    const float* __restrict__ Dv,
                                                    const short* __restrict__ xzBf,
                                                    short* __restrict__ yh) {
    int d = blockIdx.x * 128 + threadIdx.x;       // grid.x = 3
    int c = blockIdx.y, b = blockIdx.z;
    float a[DSTATE], h[DSTATE];
#pragma unroll
    for (int s = 0; s < DSTATE; s++)
        a[s] = -expf(A_log[(size_t)d * DSTATE + s]);   // precise (once per lane)
    const float* hi = hInit + (((size_t)b * CHUNKS + c) * DINNER + d) * DSTATE;
#pragma unroll
    for (int g = 0; g < 4; g++)
        *(float4*)&h[g * 4] = *(const float4*)&hi[g * 4];
    float Dd = Dv[d];
    size_t rbase = (size_t)b * NP + (size_t)c * LC;
    for (int l = 0; l < LC; l++) {
        size_t r = rbase + l;
        float dtv = bf2f((unsigned short)dtB[r * DINNER + d]);
        float u = bf2f((unsigned short)xcB[r * DINNER + d]);
        float du = dtv * u;
        const float* pb = projBC + r * 32;        // wave-uniform
        float Bv[DSTATE], Cv[DSTATE];
        *(float4*)&Bv[0]  = *(const float4*)&pb[0];
        *(float4*)&Bv[4]  = *(const float4*)&pb[4];
        *(float4*)&Bv[8]  = *(const float4*)&pb[8];
        *(float4*)&Bv[12] = *(const float4*)&pb[12];
        *(float4*)&Cv[0]  = *(const float4*)&pb[16];
        *(float4*)&Cv[4]  = *(const float4*)&pb[20];
        *(float4*)&Cv[8]  = *(const float4*)&pb[24];
        *(float4*)&Cv[12] = *(const float4*)&pb[28];
        float y = 0.f;
#pragma unroll
        for (int s = 0; s < DSTATE; s++) {
            float dA = __expf(dtv * a[s]);        // fast exp (hot loop)
            h[s] = h[s] * dA + du * Bv[s];
            y = fmaf(h[s], Cv[s], y);
        }
        float z = bf2f((unsigned short)xzBf[r * 768 + DINNER + d]);
        float val = (y + u * Dd) * (z / (1.f + __expf(-z)));
        yh[r * DINNER + d] = (short)f2bf_rne(val);
    }
}

// ---------------- final layernorm: per-row stats (bf16 x input) ----------------
__global__ __launch_bounds__(256) void ln_stats_kernel(const short* __restrict__ xh,
                                                       float* __restrict__ stats) {
    int r = blockIdx.x * 4 + (threadIdx.x >> 6);
    int lane = threadIdx.x & 63;
    if (r >= RTOT) return;
    float s = 0.f, ss = 0.f;
    for (int c = lane; c < DM; c += 64) {
        float v = bf2f((unsigned short)xh[(size_t)r * DM + c]);
        s += v;
        ss += v * v;
    }
#pragma unroll
    for (int o = 32; o > 0; o >>= 1) {
        s += __shfl_down(s, o);
        ss += __shfl_down(ss, o);
    }
    if (lane == 0) {
        float mu = s / (float)DM;
        float var = ss / (float)DM - mu * mu;
        stats[r * 2] = mu;
        stats[r * 2 + 1] = rsqrtf(var + 1e-5f);
    }
}

// ---------------- normalized mean over sequence (bf16 x input) ----------------
__global__ __launch_bounds__(256) void ln_mean_kernel(const short* __restrict__ xh,
                                                      const float* __restrict__ stats,
                                                      const float* __restrict__ nw,
                                                      const float* __restrict__ nb,
                                                      float* __restrict__ out) {
    int idx = blockIdx.x * 256 + threadIdx.x;
    if (idx >= BB * DM) return;
    int c = idx % DM;
    int b = idx / DM;
    float acc = 0.f;
    for (int l = 0; l < NP; l++) {
        size_t r = (size_t)b * NP + l;
        float v = bf2f((unsigned short)xh[r * DM + c]);
        acc += (v - stats[r * 2]) * stats[r * 2 + 1];
    }
    out[idx] = acc * (1.f / (float)NP) * nw[c] + nb[c];
}

extern "C" void kernel_launch(void* const* d_in, const int* in_sizes, int n_in,
                              void* d_out, int out_size, void* d_ws, size_t ws_size,
                              hipStream_t stream) {
    const float* img     = (const float*)d_in[0];
    const float* patch_w = (const float*)d_in[1];
    const float* patch_b = (const float*)d_in[2];
    const float* in_w    = (const float*)d_in[3];
    const float* conv_w  = (const float*)d_in[4];
    const float* conv_b  = (const float*)d_in[5];
    const float* xpw     = (const float*)d_in[6];
    const float* dtw     = (const float*)d_in[7];
    const float* dtb     = (const float*)d_in[8];
    const float* A_log   = (const float*)d_in[9];
    const float* Dv      = (const float*)d_in[10];
    const float* outw    = (const float*)d_in[11];
    const float* norm_w  = (const float*)d_in[12];
    const float* norm_b  = (const float*)d_in[13];
    float* out = (float*)d_out;

    float* ws = (float*)d_ws;
    const size_t R = RTOT;
    const size_t SCN = (size_t)BB * CHUNKS * DINNER * DSTATE;   // 5,505,024 fu

    float* xA      = ws;                       // x bf16: R*DM shorts = 1,204,224 fu
    float* xB      = xA + R * DM / 2;
    float* xzB     = xB + R * DM / 2;          // xz bf16: R*768 shorts = 4,816,896 fu (also im2col col)
    float* xcB     = xzB + R * 768 / 2;        // xc bf16: R*384 shorts = 2,408,448 fu
    float* dtBf    = xcB + R * DINNER / 2;     // dt bf16: 2,408,448 fu
    float* projBC  = dtBf + R * DINNER / 2;    // R*32 fp32 = 401,408 fu
    float* scratch = projBC + R * 32;          // 2*SCN shared (partials / hEnd+prodDA / y2)
    float* wAll    = scratch + 2 * SCN;        // packed weights
    float* stats   = wAll + 4644864;           // R*2

    // packed weight layout (shorts within wAll)
    short* wPatch = (short*)wAll;                           // 192*768          = 147,456
    short* wIn    = wPatch + (size_t)DM * 768;              // 24*768*192       = 3,538,944
    short* wOut   = wIn + (size_t)DEPTH * 2 * DINNER * DM;  // 24*192*384       = 1,769,472
    short* wCmb   = wOut + (size_t)DEPTH * DM * DINNER;     // 24*416*384       = 3,833,856

    short* y2h = (short*)scratch;              // y2 bf16 (dead hEnd region)
    float* pkparts = scratch + SCN;            // out_proj SK2 partials (dead hInit region)

    // ---- pre-pack weights + build combined xproj/dt weight (once) ----
    pack_w_kernel<<<dim3((DM * 768 / 4 + 255) / 256), 256, 0, stream>>>(
        patch_w, wPatch, DM * 768);
    pack_w_kernel<<<dim3((DEPTH * 2 * DINNER * DM / 4 + 255) / 256), 256, 0, stream>>>(
        in_w, wIn, DEPTH * 2 * DINNER * DM);
    pack_w_kernel<<<dim3((DEPTH * DM * DINNER / 4 + 255) / 256), 256, 0, stream>>>(
        outw, wOut, DEPTH * DM * DINNER);
    wcmb_kernel<<<dim3((DEPTH * NCMB * DINNER + 255) / 256), 256, 0, stream>>>(
        xpw, dtw, wCmb);

    // ---- patch embed: bf16 im2col + SK4 GEMM + reduce(+bias) -> bf16 x ----
    {
        short* colH = (short*)xzB;
        size_t n = R * 768;
        im2col_pack_kernel<<<dim3((unsigned)((n + 255) / 256)), 256, 0, stream>>>(img, colH);
        gemm_pk_kernel<64><<<dim3(3, RTOT / 128, 4), 256, 0, stream>>>(
            colH, wPatch, scratch, nullptr, nullptr, RTOT, DM, 768, 192);
        long MN = (long)RTOT * DM;
        reduce_kernel<<<dim3((unsigned)((MN / 4 + 255) / 256)), 256, 0, stream>>>(
            scratch, nullptr, (short*)xA, patch_b, MN, DM, 4);
    }

    float* xin = xA;
    float* xout = xB;
    for (int layer = 0; layer < DEPTH; layer++) {
        const float* conv_wl = conv_w + (size_t)layer * DINNER * DCONV;
        const float* conv_bl = conv_b + (size_t)layer * DINNER;
        const float* dtb_l   = dtb + (size_t)layer * DINNER;
        const float* Alog_l  = A_log + (size_t)layer * DINNER * DSTATE;
        const float* Dv_l    = Dv + (size_t)layer * DINNER;
        short* wIn_l  = wIn + (size_t)layer * 2 * DINNER * DM;
        short* wOut_l = wOut + (size_t)layer * DM * DINNER;
        short* wCmb_l = wCmb + (size_t)layer * NCMB * DINNER;

        short* xinH = (short*)xin;
        short* xoutH = (short*)xout;
        short* xzH = (short*)xzB;
        short* xcH = (short*)xcB;
        short* dtH = (short*)dtBf;

        // xz(bf16) = x @ in_w^T   (M=12544, N=768, K=192), direct bf16 out
        gemm_pk_kernel<128><<<dim3(768 / 128, RTOT / 128, 1), 256, 0, stream>>>(
            xinH, wIn_l, nullptr, xzH, nullptr, RTOT, 2 * DINNER, DM, DM);
        // xc(bf16) = silu(causal depthwise conv(xs bf16))
        {
            size_t n = R * DINNER;
            conv_silu_kernel<<<dim3((unsigned)((n + 255) / 256)), 256, 0, stream>>>(
                xzH, conv_wl, conv_bl, xcH);
        }
        // fused xproj: [B,C -> projBC fp32 | dt -> softplus bf16]  (N=416, K=384)
        gemm_xproj_kernel<<<dim3(7, RTOT / 128), 256, 0, stream>>>(
            xcH, wCmb_l, projBC, dtH, dtb_l, RTOT, DINNER);
        // chunked scan; scanC emits y2 bf16 into dead hEnd region
        scanA_kernel<<<dim3(3, CHUNKS, BB), 128, 0, stream>>>(
            xcH, projBC, dtH, Alog_l, scratch, scratch + SCN);
        scanB_kernel<<<dim3((BB * DINNER * DSTATE + 255) / 256), 256, 0, stream>>>(
            scratch, scratch + SCN);
        scanC_kernel<<<dim3(3, CHUNKS, BB), 128, 0, stream>>>(
            xcH, projBC, dtH, scratch + SCN, Alog_l, Dv_l, xzH, y2h);
        // x_next = y2 @ outw^T (N=192, K=384) SK=2 + reduce -> bf16 xout
        gemm_pk_kernel<64><<<dim3(DM / 64, RTOT / 128, 2), 256, 0, stream>>>(
            y2h, wOut_l, pkparts, nullptr, nullptr, RTOT, DM, DINNER, 192);
        {
            long MN = (long)RTOT * DM;
            reduce_kernel<<<dim3((unsigned)((MN / 4 + 255) / 256)), 256, 0, stream>>>(
                pkparts, nullptr, xoutH, nullptr, MN, DM, 2);
        }

        float* t = xin; xin = xout; xout = t;
    }

    // final layernorm + mean over sequence (bf16 x)
    short* xfH = (short*)xin;
    ln_stats_kernel<<<dim3(RTOT / 4), 256, 0, stream>>>(xfH, stats);
    ln_mean_kernel<<<dim3((BB * DM + 255) / 256), 256, 0, stream>>>(
        xfH, stats, norm_w, norm_b, out);
}

// Round 14
// 3417.543 us; speedup vs baseline: 1.5891x; 1.0366x over previous
//
#include <hip/hip_runtime.h>
#include <hip/hip_bf16.h>
#include <math.h>

#define BB 64
#define IMG 224
#define PP 16
#define CIN 3
#define DM 192
#define DEPTH 24
#define DSTATE 16
#define DINNER 384
#define DTR 12
#define DCONV 4
#define NP 196              // (224/16)^2
#define RTOT (BB * NP)      // 12544 rows
#define CHUNKS 14
#define LC 14               // NP / CHUNKS
#define NCMB (2 * DSTATE + DINNER)   // 416 = B,C (32) + dt (384)

typedef short bf16x8 __attribute__((ext_vector_type(8)));
typedef float f32x4 __attribute__((ext_vector_type(4)));

__device__ inline unsigned short f2bf_rne(float f) {
    unsigned u = __float_as_uint(f);
    unsigned r = u + 0x7fffu + ((u >> 16) & 1u);
    return (unsigned short)(r >> 16);
}
__device__ inline float bf2f(unsigned short s) {
    return __uint_as_float(((unsigned)s) << 16);
}

// ---------------- im2col for patch embed, emitting bf16 ----------------
__global__ __launch_bounds__(256) void im2col_pack_kernel(const float* __restrict__ img,
                                                          short* __restrict__ colH) {
    size_t idx = (size_t)blockIdx.x * 256 + threadIdx.x;
    if (idx >= (size_t)RTOT * 768) return;
    int t = (int)(idx % 768);
    size_t r = idx / 768;
    int l = (int)(r % NP);
    int b = (int)(r / NP);
    int ph = l / 14, pw = l % 14;
    int ci = t / 256, rem = t % 256;
    int i = rem / 16, j = rem % 16;
    float v = img[(((size_t)b * CIN + ci) * IMG + ph * 16 + i) * IMG + pw * 16 + j];
    colH[idx] = (short)f2bf_rne(v);
}

// ---------------- weight pack: fp32[NE] -> bf16 ----------------
__global__ __launch_bounds__(256) void pack_w_kernel(const float* __restrict__ W,
                                                     short* __restrict__ Wh, int NE) {
    int i = blockIdx.x * 256 + threadIdx.x;
    if (i * 4 >= NE) return;
    float4 v = *(const float4*)&W[i * 4];
    short4 h;
    h.x = (short)f2bf_rne(v.x);
    h.y = (short)f2bf_rne(v.y);
    h.z = (short)f2bf_rne(v.z);
    h.w = (short)f2bf_rne(v.w);
    *(short4*)&Wh[i * 4] = h;
}

// ---------------- combined xproj weight: [DEPTH][416][384] bf16 ----------------
// rows 0..31 = xpw rows 12..43 (B then C); rows 32..415 = dtw·xpw[0:12] fold.
__global__ __launch_bounds__(256) void wcmb_kernel(const float* __restrict__ xpw,
                                                   const float* __restrict__ dtw,
                                                   short* __restrict__ wCmb) {
    int idx = blockIdx.x * 256 + threadIdx.x;
    if (idx >= DEPTH * NCMB * DINNER) return;
    int layer = idx / (NCMB * DINNER);
    int rem = idx % (NCMB * DINNER);
    int n = rem / DINNER;
    int k = rem % DINNER;
    const float* xp = xpw + (size_t)layer * 44 * DINNER;
    float v;
    if (n < 32) {
        v = xp[(DTR + n) * DINNER + k];
    } else {
        int d = n - 32;
        const float* w = dtw + ((size_t)layer * DINNER + d) * DTR;
        v = 0.f;
#pragma unroll
        for (int j = 0; j < DTR; j++) v += w[j] * xp[j * DINNER + k];
    }
    wCmb[idx] = (short)f2bf_rne(v);
}

// ---------------- bf16 MFMA GEMM, double-buffered LDS, 1 barrier/k-iter ----------------
// C[M,N] = A[M,K] * B[N,K]^T. BM in {64,128}; 4 waves arranged (BM/64) x (4/(BM/64)).
// gridDim.z==1: direct write to bf16 CBf if non-null else fp32 C (+bias);
// else partial z at C + z*M*N. M%BM==0, Kc%32==0; B rows masked vs N.
template<int BM, int BN>
__global__ __launch_bounds__(256) void gemm_pk_kernel(const short* __restrict__ Ah,
                                                      const short* __restrict__ Bh,
                                                      float* __restrict__ C,
                                                      short* __restrict__ CBf,
                                                      const float* __restrict__ bias,
                                                      int M, int N, int K, int Kc) {
    constexpr int BK = 32;
    constexpr int LDSS = BK + 8;                // 40 shorts = 80 B row stride
    constexpr int WR = BM / 64;                 // wave rows
    constexpr int WC = 4 / WR;                  // wave cols
    constexpr int NJ = BN / WC / 16;            // n-frags per wave
    constexpr int A8 = BM / 64;                 // short8 loads/thread (A)
    constexpr int B8 = BN / 64;                 // short8 loads/thread (B)
    __shared__ short As[2][BM * LDSS];
    __shared__ short Bs[2][BN * LDSS];

    const int tid = threadIdx.x;
    const int lane = tid & 63;
    const int wid = tid >> 6;
    const int wr = wid / WC, wc = wid % WC;
    const int row0 = blockIdx.y * BM, col0 = blockIdx.x * BN;
    const int kbase = blockIdx.z * Kc;
    const bf16x8 ZV = {0, 0, 0, 0, 0, 0, 0, 0};

    bf16x8 aPh[A8], bPh[B8];
    f32x4 acc[4][NJ] = {};

    auto loadG = [&](int k0) {
#pragma unroll
        for (int i = 0; i < A8; i++) {
            int lin = tid + i * 256;
            int r = lin >> 2, cg = (lin & 3) * 8;
            aPh[i] = *(const bf16x8*)&Ah[(size_t)(row0 + r) * K + k0 + cg];
        }
#pragma unroll
        for (int i = 0; i < B8; i++) {
            int lin = tid + i * 256;
            int r = lin >> 2, cg = (lin & 3) * 8;
            int n = col0 + r;
            bPh[i] = (n < N) ? *(const bf16x8*)&Bh[(size_t)n * K + k0 + cg] : ZV;
        }
    };
    auto storeLDS = [&](int p) {
#pragma unroll
        for (int i = 0; i < A8; i++) {
            int lin = tid + i * 256;
            int r = lin >> 2, cg = (lin & 3) * 8;
            *(bf16x8*)&As[p][r * LDSS + cg] = aPh[i];
        }
#pragma unroll
        for (int i = 0; i < B8; i++) {
            int lin = tid + i * 256;
            int r = lin >> 2, cg = (lin & 3) * 8;
            *(bf16x8*)&Bs[p][r * LDSS + cg] = bPh[i];
        }
    };
    auto compute = [&](int p) {
        const int fr = lane & 15;
        const int kg = (lane >> 4) * 8;
        bf16x8 aH[4], bH[NJ];
#pragma unroll
        for (int i = 0; i < 4; i++)
            aH[i] = *(const bf16x8*)&As[p][(wr * 64 + i * 16 + fr) * LDSS + kg];
#pragma unroll
        for (int j = 0; j < NJ; j++)
            bH[j] = *(const bf16x8*)&Bs[p][(wc * (BN / WC) + j * 16 + fr) * LDSS + kg];
#pragma unroll
        for (int i = 0; i < 4; i++)
#pragma unroll
            for (int j = 0; j < NJ; j++)
                acc[i][j] = __builtin_amdgcn_mfma_f32_16x16x32_bf16(aH[i], bH[j], acc[i][j], 0, 0, 0);
    };

    loadG(kbase);
    storeLDS(0);
    __syncthreads();
    int p = 0;
    for (int k0 = kbase + BK;; k0 += BK) {
        const bool has_next = (k0 < kbase + Kc);
        if (has_next) loadG(k0);     // next-tile loads in flight under MFMAs
        compute(p);
        if (!has_next) break;
        storeLDS(p ^ 1);             // other buffer; reads of it finished pre-barrier
        __syncthreads();             // single barrier per k-iter
        p ^= 1;
    }

    const bool direct = (gridDim.z == 1);
    float* Cout = C + (size_t)blockIdx.z * M * N;
    const int crow = (lane >> 4) * 4;
    const int ccol = lane & 15;
#pragma unroll
    for (int i = 0; i < 4; i++)
#pragma unroll
        for (int j = 0; j < NJ; j++) {
            int gn = col0 + wc * (BN / WC) + j * 16 + ccol;
            if (gn >= N) continue;
            int gm0 = row0 + wr * 64 + i * 16 + crow;
            float bv = (direct && bias) ? bias[gn] : 0.f;
            if (direct && CBf) {
#pragma unroll
                for (int reg = 0; reg < 4; reg++)
                    CBf[(size_t)(gm0 + reg) * N + gn] = (short)f2bf_rne(acc[i][j][reg] + bv);
            } else {
#pragma unroll
                for (int reg = 0; reg < 4; reg++)
                    Cout[(size_t)(gm0 + reg) * N + gn] = acc[i][j][reg] + bv;
            }
        }
}

// ---------------- fused xproj GEMM (BM=64, BN=64, full coverage) ----------------
// [B,C | dt] = xc @ wCmb^T, N=NCMB=416. 4 waves of 64x16: wave wc covers cols
// col0+wc*16..+15. cols 0..31 -> projBC fp32 (stride 32); cols 32..415 ->
// dt bf16 = softplus(acc + dtb[col-32]) (stride 384). Double-buffered.
__global__ __launch_bounds__(256) void gemm_xproj_kernel(const short* __restrict__ Ah,
                                                         const short* __restrict__ Bh,
                                                         float* __restrict__ projBC,
                                                         short* __restrict__ dtB,
                                                         const float* __restrict__ dtb,
                                                         int M, int K) {
    constexpr int BM = 64, BN = 64, BK = 32;
    constexpr int LDSS = BK + 8;
    constexpr int N = NCMB;
    __shared__ short As[2][BM * LDSS];
    __shared__ short Bs[2][BN * LDSS];

    const int tid = threadIdx.x;
    const int lane = tid & 63;
    const int wc = tid >> 6;                    // 4 waves, 16 cols each
    const int row0 = blockIdx.y * BM, col0 = blockIdx.x * BN;
    const bf16x8 ZV = {0, 0, 0, 0, 0, 0, 0, 0};

    bf16x8 aPh, bPh;
    f32x4 acc[4] = {};

    auto loadG = [&](int k0) {
        {
            int r = tid >> 2, cg = (tid & 3) * 8;
            aPh = *(const bf16x8*)&Ah[(size_t)(row0 + r) * K + k0 + cg];
            int n = col0 + r;
            bPh = (n < N) ? *(const bf16x8*)&Bh[(size_t)n * K + k0 + cg] : ZV;
        }
    };
    auto storeLDS = [&](int p) {
        int r = tid >> 2, cg = (tid & 3) * 8;
        *(bf16x8*)&As[p][r * LDSS + cg] = aPh;
        *(bf16x8*)&Bs[p][r * LDSS + cg] = bPh;
    };
    auto compute = [&](int p) {
        const int fr = lane & 15;
        const int kg = (lane >> 4) * 8;
        bf16x8 aH[4], bH;
#pragma unroll
        for (int i = 0; i < 4; i++)
            aH[i] = *(const bf16x8*)&As[p][(i * 16 + fr) * LDSS + kg];
        bH = *(const bf16x8*)&Bs[p][(wc * 16 + fr) * LDSS + kg];
#pragma unroll
        for (int i = 0; i < 4; i++)
            acc[i] = __builtin_amdgcn_mfma_f32_16x16x32_bf16(aH[i], bH, acc[i], 0, 0, 0);
    };

    loadG(0);
    storeLDS(0);
    __syncthreads();
    int p = 0;
    for (int k0 = BK;; k0 += BK) {
        const bool has_next = (k0 < K);
        if (has_next) loadG(k0);
        compute(p);
        if (!has_next) break;
        storeLDS(p ^ 1);
        __syncthreads();
        p ^= 1;
    }

    const int crow = (lane >> 4) * 4;
    const int ccol = lane & 15;
#pragma unroll
    for (int i = 0; i < 4; i++) {
        int gn = col0 + wc * 16 + ccol;
        if (gn >= NCMB) continue;
        int gm0 = row0 + i * 16 + crow;
        if (gn < 32) {
#pragma unroll
            for (int reg = 0; reg < 4; reg++)
                projBC[(size_t)(gm0 + reg) * 32 + gn] = acc[i][reg];
        } else {
            int d = gn - 32;
            float bv = dtb[d];
#pragma unroll
            for (int reg = 0; reg < 4; reg++) {
                float v = acc[i][reg] + bv;
                v = (v > 20.f) ? v : __logf(1.f + __expf(v));   // softplus
                dtB[(size_t)(gm0 + reg) * DINNER + d] = (short)f2bf_rne(v);
            }
        }
    }
}

// ---------------- split-K reduce: sum parts (+bias); fp32 OR packed bf16 output ----------------
__global__ __launch_bounds__(256) void reduce_kernel(const float* __restrict__ parts,
                                                     float* __restrict__ Cf,
                                                     short* __restrict__ outH,
                                                     const float* __restrict__ bias,
                                                     long MN, int N, int SK) {
    long i = (long)blockIdx.x * 256 + threadIdx.x;
    if (i * 4 >= MN) return;
    float4 acc = *(const float4*)&parts[i * 4];
    for (int z = 1; z < SK; z++) {
        float4 v = *(const float4*)&parts[(size_t)z * MN + i * 4];
        acc.x += v.x; acc.y += v.y; acc.z += v.z; acc.w += v.w;
    }
    if (bias) {
        int col = (int)((i * 4) % N);
        float4 bv = *(const float4*)&bias[col];
        acc.x += bv.x; acc.y += bv.y; acc.z += bv.z; acc.w += bv.w;
    }
    if (outH) {
        short4 h;
        h.x = (short)f2bf_rne(acc.x);
        h.y = (short)f2bf_rne(acc.y);
        h.z = (short)f2bf_rne(acc.z);
        h.w = (short)f2bf_rne(acc.w);
        *(short4*)&outH[i * 4] = h;
    } else {
        *(float4*)&Cf[i * 4] = acc;
    }
}

// ---------------- causal depthwise conv (DCONV=4) + SiLU; bf16 in, bf16 out ----------------
__global__ __launch_bounds__(256) void conv_silu_kernel(const short* __restrict__ xzBf,
                                                        const float* __restrict__ cw,
                                                        const float* __restrict__ cb,
                                                        short* __restrict__ xcH) {
    size_t idx = (size_t)blockIdx.x * 256 + threadIdx.x;
    if (idx >= (size_t)RTOT * DINNER) return;
    int e = (int)(idx % DINNER);
    size_t r = idx / DINNER;
    int l = (int)(r % NP);
    size_t b = r / NP;
    const float* w = cw + (size_t)e * DCONV;
    float acc = cb[e];
#pragma unroll
    for (int k = 0; k < DCONV; k++) {
        int ls = l + k - (DCONV - 1);
        if (ls >= 0) acc += bf2f((unsigned short)xzBf[(b * NP + ls) * 768 + e]) * w[k];
    }
    float val = acc / (1.f + __expf(-acc));   // silu (fast exp)
    xcH[idx] = (short)f2bf_rne(val);
}

// ---------------- chunked selective scan: lane owns (b,d), 16 states in regs ----------------
__global__ __launch_bounds__(128) void scanA_kernel(const short* __restrict__ xcB,
                                                    const float* __restrict__ projBC,
                                                    const short* __restrict__ dtB,
                                                    const float* __restrict__ A_log,
                                                    float* __restrict__ hEnd,
                                                    float* __restrict__ prodDA) {
    int d = blockIdx.x * 128 + threadIdx.x;       // grid.x = 3
    int c = blockIdx.y, b = blockIdx.z;
    float a[DSTATE], h[DSTATE], p[DSTATE];
#pragma unroll
    for (int s = 0; s < DSTATE; s++) {
        a[s] = -expf(A_log[(size_t)d * DSTATE + s]);   // precise (once per lane)
        h[s] = 0.f;
        p[s] = 1.f;
    }
    size_t rbase = (size_t)b * NP + (size_t)c * LC;
    for (int l = 0; l < LC; l++) {
        size_t r = rbase + l;
        float dtv = bf2f((unsigned short)dtB[r * DINNER + d]);
        float du = dtv * bf2f((unsigned short)xcB[r * DINNER + d]);
        const float* pb = projBC + r * 32;        // wave-uniform
        float Bv[DSTATE];
        *(float4*)&Bv[0]  = *(const float4*)&pb[0];
        *(float4*)&Bv[4]  = *(const float4*)&pb[4];
        *(float4*)&Bv[8]  = *(const float4*)&pb[8];
        *(float4*)&Bv[12] = *(const float4*)&pb[12];
#pragma unroll
        for (int s = 0; s < DSTATE; s++) {
            float dA = __expf(dtv * a[s]);        // fast exp (hot loop)
            h[s] = h[s] * dA + du * Bv[s];
            p[s] *= dA;
        }
    }
    float* he = hEnd   + (((size_t)b * CHUNKS + c) * DINNER + d) * DSTATE;
    float* pd = prodDA + (((size_t)b * CHUNKS + c) * DINNER + d) * DSTATE;
#pragma unroll
    for (int g = 0; g < 4; g++) {
        *(float4*)&he[g * 4] = *(float4*)&h[g * 4];
        *(float4*)&pd[g * 4] = *(float4*)&p[g * 4];
    }
}

__global__ __launch_bounds__(256) void scanB_kernel(const float* __restrict__ hEnd,
                                                    float* __restrict__ prodDA) {
    int idx = blockIdx.x * 256 + threadIdx.x;
    if (idx >= BB * DINNER * DSTATE) return;
    int b = idx / (DINNER * DSTATE);
    int rem = idx % (DINNER * DSTATE);
    float run = 0.f;
    for (int c = 0; c < CHUNKS; c++) {
        size_t off = ((size_t)b * CHUNKS + c) * (DINNER * DSTATE) + rem;
        float p = prodDA[off];
        float e = hEnd[off];
        prodDA[off] = run;          // hInit for chunk c
        run = run * p + e;
    }
}

// Pass C: rerun from hInit; fused (y+u*D)*silu(z) [z from bf16 xz]; emits y2 bf16.
__global__ __launch_bounds__(128) void scanC_kernel(const short* __restrict__ xcB,
                                                    const float* __restrict__ projBC,
                                                    const short* __restrict__ dtB,
                                                    const float* __restrict__ hInit,
                                                    const float* __restrict__ A_log,
                                                    const float* __restrict__ Dv,
                                                    const short* __restrict__ xzBf,
                                                    short* __restrict__ yh) {
    int d = blockIdx.x * 128 + threadIdx.x;       // grid.x = 3
    int c = blockIdx.y, b = blockIdx.z;
    float a[DSTATE], h[DSTATE];
#pragma unroll
    for (int s = 0; s < DSTATE; s++)
        a[s] = -expf(A_log[(size_t)d * DSTATE + s]);   // precise (once per lane)
    const float* hi = hInit + (((size_t)b * CHUNKS + c) * DINNER + d) * DSTATE;
#pragma unroll
    for (int g = 0; g < 4; g++)
        *(float4*)&h[g * 4] = *(const float4*)&hi[g * 4];
    float Dd = Dv[d];
    size_t rbase = (size_t)b * NP + (size_t)c * LC;
    for (int l = 0; l < LC; l++) {
        size_t r = rbase + l;
        float dtv = bf2f((unsigned short)dtB[r * DINNER + d]);
        float u = bf2f((unsigned short)xcB[r * DINNER + d]);
        float du = dtv * u;
        const float* pb = projBC + r * 32;        // wave-uniform
        float Bv[DSTATE], Cv[DSTATE];
        *(float4*)&Bv[0]  = *(const float4*)&pb[0];
        *(float4*)&Bv[4]  = *(const float4*)&pb[4];
        *(float4*)&Bv[8]  = *(const float4*)&pb[8];
        *(float4*)&Bv[12] = *(const float4*)&pb[12];
        *(float4*)&Cv[0]  = *(const float4*)&pb[16];
        *(float4*)&Cv[4]  = *(const float4*)&pb[20];
        *(float4*)&Cv[8]  = *(const float4*)&pb[24];
        *(float4*)&Cv[12] = *(const float4*)&pb[28];
        float y = 0.f;
#pragma unroll
        for (int s = 0; s < DSTATE; s++) {
            float dA = __expf(dtv * a[s]);        // fast exp (hot loop)
            h[s] = h[s] * dA + du * Bv[s];
            y = fmaf(h[s], Cv[s], y);
        }
        float z = bf2f((unsigned short)xzBf[r * 768 + DINNER + d]);
        float val = (y + u * Dd) * (z / (1.f + __expf(-z)));
        yh[r * DINNER + d] = (short)f2bf_rne(val);
    }
}

// ---------------- final layernorm: per-row stats (bf16 x input) ----------------
__global__ __launch_bounds__(256) void ln_stats_kernel(const short* __restrict__ xh,
                                                       float* __restrict__ stats) {
    int r = blockIdx.x * 4 + (threadIdx.x >> 6);
    int lane = threadIdx.x & 63;
    if (r >= RTOT) return;
    float s = 0.f, ss = 0.f;
    for (int c = lane; c < DM; c += 64) {
        float v = bf2f((unsigned short)xh[(size_t)r * DM + c]);
        s += v;
        ss += v * v;
    }
#pragma unroll
    for (int o = 32; o > 0; o >>= 1) {
        s += __shfl_down(s, o);
        ss += __shfl_down(ss, o);
    }
    if (lane == 0) {
        float mu = s / (float)DM;
        float var = ss / (float)DM - mu * mu;
        stats[r * 2] = mu;
        stats[r * 2 + 1] = rsqrtf(var + 1e-5f);
    }
}

// ---------------- normalized mean over sequence (bf16 x input) ----------------
__global__ __launch_bounds__(256) void ln_mean_kernel(const short* __restrict__ xh,
                                                      const float* __restrict__ stats,
                                                      const float* __restrict__ nw,
                                                      const float* __restrict__ nb,
                                                      float* __restrict__ out) {
    int idx = blockIdx.x * 256 + threadIdx.x;
    if (idx >= BB * DM) return;
    int c = idx % DM;
    int b = idx / DM;
    float acc = 0.f;
    for (int l = 0; l < NP; l++) {
        size_t r = (size_t)b * NP + l;
        float v = bf2f((unsigned short)xh[r * DM + c]);
        acc += (v - stats[r * 2]) * stats[r * 2 + 1];
    }
    out[idx] = acc * (1.f / (float)NP) * nw[c] + nb[c];
}

extern "C" void kernel_launch(void* const* d_in, const int* in_sizes, int n_in,
                              void* d_out, int out_size, void* d_ws, size_t ws_size,
                              hipStream_t stream) {
    const float* img     = (const float*)d_in[0];
    const float* patch_w = (const float*)d_in[1];
    const float* patch_b = (const float*)d_in[2];
    const float* in_w    = (const float*)d_in[3];
    const float* conv_w  = (const float*)d_in[4];
    const float* conv_b  = (const float*)d_in[5];
    const float* xpw     = (const float*)d_in[6];
    const float* dtw     = (const float*)d_in[7];
    const float* dtb     = (const float*)d_in[8];
    const float* A_log   = (const float*)d_in[9];
    const float* Dv      = (const float*)d_in[10];
    const float* outw    = (const float*)d_in[11];
    const float* norm_w  = (const float*)d_in[12];
    const float* norm_b  = (const float*)d_in[13];
    float* out = (float*)d_out;

    float* ws = (float*)d_ws;
    const size_t R = RTOT;
    const size_t SCN = (size_t)BB * CHUNKS * DINNER * DSTATE;   // 5,505,024 fu

    float* xA      = ws;                       // x bf16: R*DM shorts = 1,204,224 fu
    float* xB      = xA + R * DM / 2;
    float* xzB     = xB + R * DM / 2;          // xz bf16: R*768 shorts = 4,816,896 fu (also im2col col)
    float* xcB     = xzB + R * 768 / 2;        // xc bf16
    float* dtBf    = xcB + R * DINNER / 2;     // dt bf16
    float* projBC  = dtBf + R * DINNER / 2;    // R*32 fp32
    float* scratch = projBC + R * 32;          // 2*SCN shared (partials / hEnd+prodDA / y2)
    float* wAll    = scratch + 2 * SCN;        // packed weights
    float* stats   = wAll + 4644864;           // R*2

    // packed weight layout (shorts within wAll)
    short* wPatch = (short*)wAll;                           // 192*768
    short* wIn    = wPatch + (size_t)DM * 768;              // 24*768*192
    short* wOut   = wIn + (size_t)DEPTH * 2 * DINNER * DM;  // 24*192*384
    short* wCmb   = wOut + (size_t)DEPTH * DM * DINNER;     // 24*416*384

    short* y2h = (short*)scratch;              // y2 bf16 (dead hEnd region)
    float* pkparts = scratch + SCN;            // out_proj SK2 partials (dead hInit region)

    // ---- pre-pack weights + build combined xproj/dt weight (once) ----
    pack_w_kernel<<<dim3((DM * 768 / 4 + 255) / 256), 256, 0, stream>>>(
        patch_w, wPatch, DM * 768);
    pack_w_kernel<<<dim3((DEPTH * 2 * DINNER * DM / 4 + 255) / 256), 256, 0, stream>>>(
        in_w, wIn, DEPTH * 2 * DINNER * DM);
    pack_w_kernel<<<dim3((DEPTH * DM * DINNER / 4 + 255) / 256), 256, 0, stream>>>(
        outw, wOut, DEPTH * DM * DINNER);
    wcmb_kernel<<<dim3((DEPTH * NCMB * DINNER + 255) / 256), 256, 0, stream>>>(
        xpw, dtw, wCmb);

    // ---- patch embed: bf16 im2col + SK4 GEMM + reduce(+bias) -> bf16 x ----
    {
        short* colH = (short*)xzB;
        size_t n = R * 768;
        im2col_pack_kernel<<<dim3((unsigned)((n + 255) / 256)), 256, 0, stream>>>(img, colH);
        gemm_pk_kernel<64, 64><<<dim3(3, RTOT / 64, 4), 256, 0, stream>>>(
            colH, wPatch, scratch, nullptr, nullptr, RTOT, DM, 768, 192);
        long MN = (long)RTOT * DM;
        reduce_kernel<<<dim3((unsigned)((MN / 4 + 255) / 256)), 256, 0, stream>>>(
            scratch, nullptr, (short*)xA, patch_b, MN, DM, 4);
    }

    float* xin = xA;
    float* xout = xB;
    for (int layer = 0; layer < DEPTH; layer++) {
        const float* conv_wl = conv_w + (size_t)layer * DINNER * DCONV;
        const float* conv_bl = conv_b + (size_t)layer * DINNER;
        const float* dtb_l   = dtb + (size_t)layer * DINNER;
        const float* Alog_l  = A_log + (size_t)layer * DINNER * DSTATE;
        const float* Dv_l    = Dv + (size_t)layer * DINNER;
        short* wIn_l  = wIn + (size_t)layer * 2 * DINNER * DM;
        short* wOut_l = wOut + (size_t)layer * DM * DINNER;
        short* wCmb_l = wCmb + (size_t)layer * NCMB * DINNER;

        short* xinH = (short*)xin;
        short* xoutH = (short*)xout;
        short* xzH = (short*)xzB;
        short* xcH = (short*)xcB;
        short* dtH = (short*)dtBf;

        // xz(bf16) = x @ in_w^T   (M=12544, N=768, K=192), direct bf16 out
        gemm_pk_kernel<64, 128><<<dim3(768 / 128, RTOT / 64, 1), 256, 0, stream>>>(
            xinH, wIn_l, nullptr, xzH, nullptr, RTOT, 2 * DINNER, DM, DM);
        // xc(bf16) = silu(causal depthwise conv(xs bf16))
        {
            size_t n = R * DINNER;
            conv_silu_kernel<<<dim3((unsigned)((n + 255) / 256)), 256, 0, stream>>>(
                xzH, conv_wl, conv_bl, xcH);
        }
        // fused xproj: [B,C -> projBC fp32 | dt -> softplus bf16]  (N=416, K=384)
        gemm_xproj_kernel<<<dim3(7, RTOT / 64), 256, 0, stream>>>(
            xcH, wCmb_l, projBC, dtH, dtb_l, RTOT, DINNER);
        // chunked scan; scanC emits y2 bf16 into dead hEnd region
        scanA_kernel<<<dim3(3, CHUNKS, BB), 128, 0, stream>>>(
            xcH, projBC, dtH, Alog_l, scratch, scratch + SCN);
        scanB_kernel<<<dim3((BB * DINNER * DSTATE + 255) / 256), 256, 0, stream>>>(
            scratch, scratch + SCN);
        scanC_kernel<<<dim3(3, CHUNKS, BB), 128, 0, stream>>>(
            xcH, projBC, dtH, scratch + SCN, Alog_l, Dv_l, xzH, y2h);
        // x_next = y2 @ outw^T (N=192, K=384) SK=2 + reduce -> bf16 xout
        gemm_pk_kernel<64, 64><<<dim3(DM / 64, RTOT / 64, 2), 256, 0, stream>>>(
            y2h, wOut_l, pkparts, nullptr, nullptr, RTOT, DM, DINNER, 192);
        {
            long MN = (long)RTOT * DM;
            reduce_kernel<<<dim3((unsigned)((MN / 4 + 255) / 256)), 256, 0, stream>>>(
                pkparts, nullptr, xoutH, nullptr, MN, DM, 2);
        }

        float* t = xin; xin = xout; xout = t;
    }

    // final layernorm + mean over sequence (bf16 x)
    short* xfH = (short*)xin;
    ln_stats_kernel<<<dim3(RTOT / 4), 256, 0, stream>>>(xfH, stats);
    ln_mean_kernel<<<dim3((BB * DM + 255) / 256), 256, 0, stream>>>(
        xfH, stats, norm_w, norm_b, out);
}

// Round 15
// 3175.194 us; speedup vs baseline: 1.7104x; 1.0763x over previous
//
#include <hip/hip_runtime.h>
#include <hip/hip_bf16.h>
#include <math.h>

#define BB 64
#define IMG 224
#define PP 16
#define CIN 3
#define DM 192
#define DEPTH 24
#define DSTATE 16
#define DINNER 384
#define DTR 12
#define DCONV 4
#define NP 196              // (224/16)^2
#define RTOT (BB * NP)      // 12544 rows
#define CHUNKS 14
#define LC 14               // NP / CHUNKS
#define NCMB (2 * DSTATE + DINNER)   // 416 = B,C (32) + dt (384)

typedef short bf16x8 __attribute__((ext_vector_type(8)));
typedef float f32x4 __attribute__((ext_vector_type(4)));

__device__ inline unsigned short f2bf_rne(float f) {
    unsigned u = __float_as_uint(f);
    unsigned r = u + 0x7fffu + ((u >> 16) & 1u);
    return (unsigned short)(r >> 16);
}
__device__ inline float bf2f(unsigned short s) {
    return __uint_as_float(((unsigned)s) << 16);
}

// ---------------- im2col for patch embed, emitting bf16 ----------------
__global__ __launch_bounds__(256) void im2col_pack_kernel(const float* __restrict__ img,
                                                          short* __restrict__ colH) {
    size_t idx = (size_t)blockIdx.x * 256 + threadIdx.x;
    if (idx >= (size_t)RTOT * 768) return;
    int t = (int)(idx % 768);
    size_t r = idx / 768;
    int l = (int)(r % NP);
    int b = (int)(r / NP);
    int ph = l / 14, pw = l % 14;
    int ci = t / 256, rem = t % 256;
    int i = rem / 16, j = rem % 16;
    float v = img[(((size_t)b * CIN + ci) * IMG + ph * 16 + i) * IMG + pw * 16 + j];
    colH[idx] = (short)f2bf_rne(v);
}

// ---------------- weight pack: fp32[NE] -> bf16 ----------------
__global__ __launch_bounds__(256) void pack_w_kernel(const float* __restrict__ W,
                                                     short* __restrict__ Wh, int NE) {
    int i = blockIdx.x * 256 + threadIdx.x;
    if (i * 4 >= NE) return;
    float4 v = *(const float4*)&W[i * 4];
    short4 h;
    h.x = (short)f2bf_rne(v.x);
    h.y = (short)f2bf_rne(v.y);
    h.z = (short)f2bf_rne(v.z);
    h.w = (short)f2bf_rne(v.w);
    *(short4*)&Wh[i * 4] = h;
}

// ---------------- combined xproj weight: [DEPTH][416][384] bf16 ----------------
__global__ __launch_bounds__(256) void wcmb_kernel(const float* __restrict__ xpw,
                                                   const float* __restrict__ dtw,
                                                   short* __restrict__ wCmb) {
    int idx = blockIdx.x * 256 + threadIdx.x;
    if (idx >= DEPTH * NCMB * DINNER) return;
    int layer = idx / (NCMB * DINNER);
    int rem = idx % (NCMB * DINNER);
    int n = rem / DINNER;
    int k = rem % DINNER;
    const float* xp = xpw + (size_t)layer * 44 * DINNER;
    float v;
    if (n < 32) {
        v = xp[(DTR + n) * DINNER + k];
    } else {
        int d = n - 32;
        const float* w = dtw + ((size_t)layer * DINNER + d) * DTR;
        v = 0.f;
#pragma unroll
        for (int j = 0; j < DTR; j++) v += w[j] * xp[j * DINNER + k];
    }
    wCmb[idx] = (short)f2bf_rne(v);
}

// ---------------- bf16 MFMA GEMM, double-buffered LDS, 1 barrier/k-iter ----------------
template<int BM, int BN>
__global__ __launch_bounds__(256) void gemm_pk_kernel(const short* __restrict__ Ah,
                                                      const short* __restrict__ Bh,
                                                      float* __restrict__ C,
                                                      short* __restrict__ CBf,
                                                      const float* __restrict__ bias,
                                                      int M, int N, int K, int Kc) {
    constexpr int BK = 32;
    constexpr int LDSS = BK + 8;
    constexpr int WR = BM / 64;
    constexpr int WC = 4 / WR;
    constexpr int NJ = BN / WC / 16;
    constexpr int A8 = BM / 64;
    constexpr int B8 = BN / 64;
    __shared__ short As[2][BM * LDSS];
    __shared__ short Bs[2][BN * LDSS];

    const int tid = threadIdx.x;
    const int lane = tid & 63;
    const int wid = tid >> 6;
    const int wr = wid / WC, wc = wid % WC;
    const int row0 = blockIdx.y * BM, col0 = blockIdx.x * BN;
    const int kbase = blockIdx.z * Kc;
    const bf16x8 ZV = {0, 0, 0, 0, 0, 0, 0, 0};

    bf16x8 aPh[A8], bPh[B8];
    f32x4 acc[4][NJ] = {};

    auto loadG = [&](int k0) {
#pragma unroll
        for (int i = 0; i < A8; i++) {
            int lin = tid + i * 256;
            int r = lin >> 2, cg = (lin & 3) * 8;
            aPh[i] = *(const bf16x8*)&Ah[(size_t)(row0 + r) * K + k0 + cg];
        }
#pragma unroll
        for (int i = 0; i < B8; i++) {
            int lin = tid + i * 256;
            int r = lin >> 2, cg = (lin & 3) * 8;
            int n = col0 + r;
            bPh[i] = (n < N) ? *(const bf16x8*)&Bh[(size_t)n * K + k0 + cg] : ZV;
        }
    };
    auto storeLDS = [&](int p) {
#pragma unroll
        for (int i = 0; i < A8; i++) {
            int lin = tid + i * 256;
            int r = lin >> 2, cg = (lin & 3) * 8;
            *(bf16x8*)&As[p][r * LDSS + cg] = aPh[i];
        }
#pragma unroll
        for (int i = 0; i < B8; i++) {
            int lin = tid + i * 256;
            int r = lin >> 2, cg = (lin & 3) * 8;
            *(bf16x8*)&Bs[p][r * LDSS + cg] = bPh[i];
        }
    };
    auto compute = [&](int p) {
        const int fr = lane & 15;
        const int kg = (lane >> 4) * 8;
        bf16x8 aH[4], bH[NJ];
#pragma unroll
        for (int i = 0; i < 4; i++)
            aH[i] = *(const bf16x8*)&As[p][(wr * 64 + i * 16 + fr) * LDSS + kg];
#pragma unroll
        for (int j = 0; j < NJ; j++)
            bH[j] = *(const bf16x8*)&Bs[p][(wc * (BN / WC) + j * 16 + fr) * LDSS + kg];
#pragma unroll
        for (int i = 0; i < 4; i++)
#pragma unroll
            for (int j = 0; j < NJ; j++)
                acc[i][j] = __builtin_amdgcn_mfma_f32_16x16x32_bf16(aH[i], bH[j], acc[i][j], 0, 0, 0);
    };

    loadG(kbase);
    storeLDS(0);
    __syncthreads();
    int p = 0;
    for (int k0 = kbase + BK;; k0 += BK) {
        const bool has_next = (k0 < kbase + Kc);
        if (has_next) loadG(k0);
        compute(p);
        if (!has_next) break;
        storeLDS(p ^ 1);
        __syncthreads();
        p ^= 1;
    }

    const bool direct = (gridDim.z == 1);
    float* Cout = C + (size_t)blockIdx.z * M * N;
    const int crow = (lane >> 4) * 4;
    const int ccol = lane & 15;
#pragma unroll
    for (int i = 0; i < 4; i++)
#pragma unroll
        for (int j = 0; j < NJ; j++) {
            int gn = col0 + wc * (BN / WC) + j * 16 + ccol;
            if (gn >= N) continue;
            int gm0 = row0 + wr * 64 + i * 16 + crow;
            float bv = (direct && bias) ? bias[gn] : 0.f;
            if (direct && CBf) {
#pragma unroll
                for (int reg = 0; reg < 4; reg++)
                    CBf[(size_t)(gm0 + reg) * N + gn] = (short)f2bf_rne(acc[i][j][reg] + bv);
            } else {
#pragma unroll
                for (int reg = 0; reg < 4; reg++)
                    Cout[(size_t)(gm0 + reg) * N + gn] = acc[i][j][reg] + bv;
            }
        }
}

// ---------------- fused xproj GEMM (BM=64, BN=64, full coverage) ----------------
__global__ __launch_bounds__(256) void gemm_xproj_kernel(const short* __restrict__ Ah,
                                                         const short* __restrict__ Bh,
                                                         float* __restrict__ projBC,
                                                         short* __restrict__ dtB,
                                                         const float* __restrict__ dtb,
                                                         int M, int K) {
    constexpr int BM = 64, BN = 64, BK = 32;
    constexpr int LDSS = BK + 8;
    constexpr int N = NCMB;
    __shared__ short As[2][BM * LDSS];
    __shared__ short Bs[2][BN * LDSS];

    const int tid = threadIdx.x;
    const int lane = tid & 63;
    const int wc = tid >> 6;
    const int row0 = blockIdx.y * BM, col0 = blockIdx.x * BN;
    const bf16x8 ZV = {0, 0, 0, 0, 0, 0, 0, 0};

    bf16x8 aPh, bPh;
    f32x4 acc[4] = {};

    auto loadG = [&](int k0) {
        int r = tid >> 2, cg = (tid & 3) * 8;
        aPh = *(const bf16x8*)&Ah[(size_t)(row0 + r) * K + k0 + cg];
        int n = col0 + r;
        bPh = (n < N) ? *(const bf16x8*)&Bh[(size_t)n * K + k0 + cg] : ZV;
    };
    auto storeLDS = [&](int p) {
        int r = tid >> 2, cg = (tid & 3) * 8;
        *(bf16x8*)&As[p][r * LDSS + cg] = aPh;
        *(bf16x8*)&Bs[p][r * LDSS + cg] = bPh;
    };
    auto compute = [&](int p) {
        const int fr = lane & 15;
        const int kg = (lane >> 4) * 8;
        bf16x8 aH[4], bH;
#pragma unroll
        for (int i = 0; i < 4; i++)
            aH[i] = *(const bf16x8*)&As[p][(i * 16 + fr) * LDSS + kg];
        bH = *(const bf16x8*)&Bs[p][(wc * 16 + fr) * LDSS + kg];
#pragma unroll
        for (int i = 0; i < 4; i++)
            acc[i] = __builtin_amdgcn_mfma_f32_16x16x32_bf16(aH[i], bH, acc[i], 0, 0, 0);
    };

    loadG(0);
    storeLDS(0);
    __syncthreads();
    int p = 0;
    for (int k0 = BK;; k0 += BK) {
        const bool has_next = (k0 < K);
        if (has_next) loadG(k0);
        compute(p);
        if (!has_next) break;
        storeLDS(p ^ 1);
        __syncthreads();
        p ^= 1;
    }

    const int crow = (lane >> 4) * 4;
    const int ccol = lane & 15;
#pragma unroll
    for (int i = 0; i < 4; i++) {
        int gn = col0 + wc * 16 + ccol;
        if (gn >= NCMB) continue;
        int gm0 = row0 + i * 16 + crow;
        if (gn < 32) {
#pragma unroll
            for (int reg = 0; reg < 4; reg++)
                projBC[(size_t)(gm0 + reg) * 32 + gn] = acc[i][reg];
        } else {
            int d = gn - 32;
            float bv = dtb[d];
#pragma unroll
            for (int reg = 0; reg < 4; reg++) {
                float v = acc[i][reg] + bv;
                v = (v > 20.f) ? v : __logf(1.f + __expf(v));   // softplus
                dtB[(size_t)(gm0 + reg) * DINNER + d] = (short)f2bf_rne(v);
            }
        }
    }
}

// ---------------- split-K reduce (patch embed only) ----------------
__global__ __launch_bounds__(256) void reduce_kernel(const float* __restrict__ parts,
                                                     short* __restrict__ outH,
                                                     const float* __restrict__ bias,
                                                     long MN, int N, int SK) {
    long i = (long)blockIdx.x * 256 + threadIdx.x;
    if (i * 4 >= MN) return;
    float4 acc = *(const float4*)&parts[i * 4];
    for (int z = 1; z < SK; z++) {
        float4 v = *(const float4*)&parts[(size_t)z * MN + i * 4];
        acc.x += v.x; acc.y += v.y; acc.z += v.z; acc.w += v.w;
    }
    if (bias) {
        int col = (int)((i * 4) % N);
        float4 bv = *(const float4*)&bias[col];
        acc.x += bv.x; acc.y += bv.y; acc.z += bv.z; acc.w += bv.w;
    }
    short4 h;
    h.x = (short)f2bf_rne(acc.x);
    h.y = (short)f2bf_rne(acc.y);
    h.z = (short)f2bf_rne(acc.z);
    h.w = (short)f2bf_rne(acc.w);
    *(short4*)&outH[i * 4] = h;
}

// ---------------- causal depthwise conv + SiLU, 4 channels/thread (vectorized) ----------------
__global__ __launch_bounds__(256) void conv_silu_kernel(const short* __restrict__ xzBf,
                                                        const float* __restrict__ cw,
                                                        const float* __restrict__ cb,
                                                        short* __restrict__ xcH) {
    size_t idx = (size_t)blockIdx.x * 256 + threadIdx.x;
    if (idx >= (size_t)RTOT * (DINNER / 4)) return;
    int e0 = (int)(idx % (DINNER / 4)) * 4;
    size_t r = idx / (DINNER / 4);
    int l = (int)(r % NP);
    size_t b = r / NP;
    float acc[4];
    {
        float4 cbv = *(const float4*)&cb[e0];
        acc[0] = cbv.x; acc[1] = cbv.y; acc[2] = cbv.z; acc[3] = cbv.w;
    }
    float4 wv[4];
#pragma unroll
    for (int j = 0; j < 4; j++) wv[j] = *(const float4*)&cw[(e0 + j) * DCONV];
#pragma unroll
    for (int k = 0; k < DCONV; k++) {
        int ls = l + k - (DCONV - 1);
        if (ls >= 0) {
            short4 xv = *(const short4*)&xzBf[(b * NP + ls) * 768 + e0];
            acc[0] += bf2f((unsigned short)xv.x) * (&wv[0].x)[k];
            acc[1] += bf2f((unsigned short)xv.y) * (&wv[1].x)[k];
            acc[2] += bf2f((unsigned short)xv.z) * (&wv[2].x)[k];
            acc[3] += bf2f((unsigned short)xv.w) * (&wv[3].x)[k];
        }
    }
    short4 o;
#pragma unroll
    for (int j = 0; j < 4; j++) {
        float v = acc[j] / (1.f + __expf(-acc[j]));   // silu
        (&o.x)[j] = (short)f2bf_rne(v);
    }
    *(short4*)&xcH[r * DINNER + e0] = o;
}

// ---------------- chunked selective scan: lane owns (b,d), 16 states in regs ----------------
__global__ __launch_bounds__(128) void scanA_kernel(const short* __restrict__ xcB,
                                                    const float* __restrict__ projBC,
                                                    const short* __restrict__ dtB,
                                                    const float* __restrict__ A_log,
                                                    float* __restrict__ hEnd,
                                                    float* __restrict__ prodDA) {
    int d = blockIdx.x * 128 + threadIdx.x;       // grid.x = 3
    int c = blockIdx.y, b = blockIdx.z;
    float a[DSTATE], h[DSTATE], p[DSTATE];
#pragma unroll
    for (int s = 0; s < DSTATE; s++) {
        a[s] = -expf(A_log[(size_t)d * DSTATE + s]);   // precise (once per lane)
        h[s] = 0.f;
        p[s] = 1.f;
    }
    size_t rbase = (size_t)b * NP + (size_t)c * LC;
    for (int l = 0; l < LC; l++) {
        size_t r = rbase + l;
        float dtv = bf2f((unsigned short)dtB[r * DINNER + d]);
        float du = dtv * bf2f((unsigned short)xcB[r * DINNER + d]);
        const float* pb = projBC + r * 32;        // wave-uniform
        float Bv[DSTATE];
        *(float4*)&Bv[0]  = *(const float4*)&pb[0];
        *(float4*)&Bv[4]  = *(const float4*)&pb[4];
        *(float4*)&Bv[8]  = *(const float4*)&pb[8];
        *(float4*)&Bv[12] = *(const float4*)&pb[12];
#pragma unroll
        for (int s = 0; s < DSTATE; s++) {
            float dA = __expf(dtv * a[s]);        // fast exp (hot loop)
            h[s] = h[s] * dA + du * Bv[s];
            p[s] *= dA;
        }
    }
    float* he = hEnd   + (((size_t)b * CHUNKS + c) * DINNER + d) * DSTATE;
    float* pd = prodDA + (((size_t)b * CHUNKS + c) * DINNER + d) * DSTATE;
#pragma unroll
    for (int g = 0; g < 4; g++) {
        *(float4*)&he[g * 4] = *(float4*)&h[g * 4];
        *(float4*)&pd[g * 4] = *(float4*)&p[g * 4];
    }
}

__global__ __launch_bounds__(256) void scanB_kernel(const float* __restrict__ hEnd,
                                                    float* __restrict__ prodDA) {
    int idx = blockIdx.x * 256 + threadIdx.x;
    if (idx >= BB * DINNER * DSTATE) return;
    int b = idx / (DINNER * DSTATE);
    int rem = idx % (DINNER * DSTATE);
    float run = 0.f;
    for (int c = 0; c < CHUNKS; c++) {
        size_t off = ((size_t)b * CHUNKS + c) * (DINNER * DSTATE) + rem;
        float p = prodDA[off];
        float e = hEnd[off];
        prodDA[off] = run;          // hInit for chunk c
        run = run * p + e;
    }
}

// Pass C: rerun from hInit; fused (y+u*D)*silu(z); emits y2 bf16.
__global__ __launch_bounds__(128) void scanC_kernel(const short* __restrict__ xcB,
                                                    const float* __restrict__ projBC,
                                                    const short* __restrict__ dtB,
                                                    const float* __restrict__ hInit,
                                                    const float* __restrict__ A_log,
                                                    const float* __restrict__ Dv,
                                                    const short* __restrict__ xzBf,
                                                    short* __restrict__ yh) {
    int d = blockIdx.x * 128 + threadIdx.x;       // grid.x = 3
    int c = blockIdx.y, b = blockIdx.z;
    float a[DSTATE], h[DSTATE];
#pragma unroll
    for (int s = 0; s < DSTATE; s++)
        a[s] = -expf(A_log[(size_t)d * DSTATE + s]);   // precise (once per lane)
    const float* hi = hInit + (((size_t)b * CHUNKS + c) * DINNER + d) * DSTATE;
#pragma unroll
    for (int g = 0; g < 4; g++)
        *(float4*)&h[g * 4] = *(const float4*)&hi[g * 4];
    float Dd = Dv[d];
    size_t rbase = (size_t)b * NP + (size_t)c * LC;
    for (int l = 0; l < LC; l++) {
        size_t r = rbase + l;
        float dtv = bf2f((unsigned short)dtB[r * DINNER + d]);
        float u = bf2f((unsigned short)xcB[r * DINNER + d]);
        float du = dtv * u;
        const float* pb = projBC + r * 32;        // wave-uniform
        float Bv[DSTATE], Cv[DSTATE];
        *(float4*)&Bv[0]  = *(const float4*)&pb[0];
        *(float4*)&Bv[4]  = *(const float4*)&pb[4];
        *(float4*)&Bv[8]  = *(const float4*)&pb[8];
        *(float4*)&Bv[12] = *(const float4*)&pb[12];
        *(float4*)&Cv[0]  = *(const float4*)&pb[16];
        *(float4*)&Cv[4]  = *(const float4*)&pb[20];
        *(float4*)&Cv[8]  = *(const float4*)&pb[24];
        *(float4*)&Cv[12] = *(const float4*)&pb[28];
        float y = 0.f;
#pragma unroll
        for (int s = 0; s < DSTATE; s++) {
            float dA = __expf(dtv * a[s]);        // fast exp (hot loop)
            h[s] = h[s] * dA + du * Bv[s];
            y = fmaf(h[s], Cv[s], y);
        }
        float z = bf2f((unsigned short)xzBf[r * 768 + DINNER + d]);
        float val = (y + u * Dd) * (z / (1.f + __expf(-z)));
        yh[r * DINNER + d] = (short)f2bf_rne(val);
    }
}

// ---------------- final layernorm: per-row stats (bf16 x input) ----------------
__global__ __launch_bounds__(256) void ln_stats_kernel(const short* __restrict__ xh,
                                                       float* __restrict__ stats) {
    int r = blockIdx.x * 4 + (threadIdx.x >> 6);
    int lane = threadIdx.x & 63;
    if (r >= RTOT) return;
    float s = 0.f, ss = 0.f;
    for (int c = lane; c < DM; c += 64) {
        float v = bf2f((unsigned short)xh[(size_t)r * DM + c]);
        s += v;
        ss += v * v;
    }
#pragma unroll
    for (int o = 32; o > 0; o >>= 1) {
        s += __shfl_down(s, o);
        ss += __shfl_down(ss, o);
    }
    if (lane == 0) {
        float mu = s / (float)DM;
        float var = ss / (float)DM - mu * mu;
        stats[r * 2] = mu;
        stats[r * 2 + 1] = rsqrtf(var + 1e-5f);
    }
}

// ---------------- normalized mean over sequence (bf16 x input) ----------------
__global__ __launch_bounds__(256) void ln_mean_kernel(const short* __restrict__ xh,
                                                      const float* __restrict__ stats,
                                                      const float* __restrict__ nw,
                                                      const float* __restrict__ nb,
                                                      float* __restrict__ out) {
    int idx = blockIdx.x * 256 + threadIdx.x;
    if (idx >= BB * DM) return;
    int c = idx % DM;
    int b = idx / DM;
    float acc = 0.f;
    for (int l = 0; l < NP; l++) {
        size_t r = (size_t)b * NP + l;
        float v = bf2f((unsigned short)xh[r * DM + c]);
        acc += (v - stats[r * 2]) * stats[r * 2 + 1];
    }
    out[idx] = acc * (1.f / (float)NP) * nw[c] + nb[c];
}

extern "C" void kernel_launch(void* const* d_in, const int* in_sizes, int n_in,
                              void* d_out, int out_size, void* d_ws, size_t ws_size,
                              hipStream_t stream) {
    const float* img     = (const float*)d_in[0];
    const float* patch_w = (const float*)d_in[1];
    const float* patch_b = (const float*)d_in[2];
    const float* in_w    = (const float*)d_in[3];
    const float* conv_w  = (const float*)d_in[4];
    const float* conv_b  = (const float*)d_in[5];
    const float* xpw     = (const float*)d_in[6];
    const float* dtw     = (const float*)d_in[7];
    const float* dtb     = (const float*)d_in[8];
    const float* A_log   = (const float*)d_in[9];
    const float* Dv      = (const float*)d_in[10];
    const float* outw    = (const float*)d_in[11];
    const float* norm_w  = (const float*)d_in[12];
    const float* norm_b  = (const float*)d_in[13];
    float* out = (float*)d_out;

    float* ws = (float*)d_ws;
    const size_t R = RTOT;
    const size_t SCN = (size_t)BB * CHUNKS * DINNER * DSTATE;   // 5,505,024 fu

    float* xA      = ws;                       // x bf16
    float* xB      = xA + R * DM / 2;
    float* xzB     = xB + R * DM / 2;          // xz bf16 (also im2col col)
    float* xcB     = xzB + R * 768 / 2;        // xc bf16
    float* dtBf    = xcB + R * DINNER / 2;     // dt bf16
    float* projBC  = dtBf + R * DINNER / 2;    // R*32 fp32
    float* scratch = projBC + R * 32;          // 2*SCN shared (patch partials / hEnd+prodDA / y2)
    float* wAll    = scratch + 2 * SCN;        // packed weights
    float* stats   = wAll + 4644864;           // R*2

    short* wPatch = (short*)wAll;                           // 192*768
    short* wIn    = wPatch + (size_t)DM * 768;              // 24*768*192
    short* wOut   = wIn + (size_t)DEPTH * 2 * DINNER * DM;  // 24*192*384
    short* wCmb   = wOut + (size_t)DEPTH * DM * DINNER;     // 24*416*384

    short* y2h = (short*)scratch;              // y2 bf16 (dead hEnd region)

    // ---- pre-pack weights + build combined xproj/dt weight (once) ----
    pack_w_kernel<<<dim3((DM * 768 / 4 + 255) / 256), 256, 0, stream>>>(
        patch_w, wPatch, DM * 768);
    pack_w_kernel<<<dim3((DEPTH * 2 * DINNER * DM / 4 + 255) / 256), 256, 0, stream>>>(
        in_w, wIn, DEPTH * 2 * DINNER * DM);
    pack_w_kernel<<<dim3((DEPTH * DM * DINNER / 4 + 255) / 256), 256, 0, stream>>>(
        outw, wOut, DEPTH * DM * DINNER);
    wcmb_kernel<<<dim3((DEPTH * NCMB * DINNER + 255) / 256), 256, 0, stream>>>(
        xpw, dtw, wCmb);

    // ---- patch embed: bf16 im2col + SK4 GEMM + reduce(+bias) -> bf16 x ----
    {
        short* colH = (short*)xzB;
        size_t n = R * 768;
        im2col_pack_kernel<<<dim3((unsigned)((n + 255) / 256)), 256, 0, stream>>>(img, colH);
        gemm_pk_kernel<64, 64><<<dim3(3, RTOT / 64, 4), 256, 0, stream>>>(
            colH, wPatch, scratch, nullptr, nullptr, RTOT, DM, 768, 192);
        long MN = (long)RTOT * DM;
        reduce_kernel<<<dim3((unsigned)((MN / 4 + 255) / 256)), 256, 0, stream>>>(
            scratch, (short*)xA, patch_b, MN, DM, 4);
    }

    float* xin = xA;
    float* xout = xB;
    for (int layer = 0; layer < DEPTH; layer++) {
        const float* conv_wl = conv_w + (size_t)layer * DINNER * DCONV;
        const float* conv_bl = conv_b + (size_t)layer * DINNER;
        const float* dtb_l   = dtb + (size_t)layer * DINNER;
        const float* Alog_l  = A_log + (size_t)layer * DINNER * DSTATE;
        const float* Dv_l    = Dv + (size_t)layer * DINNER;
        short* wIn_l  = wIn + (size_t)layer * 2 * DINNER * DM;
        short* wOut_l = wOut + (size_t)layer * DM * DINNER;
        short* wCmb_l = wCmb + (size_t)layer * NCMB * DINNER;

        short* xinH = (short*)xin;
        short* xoutH = (short*)xout;
        short* xzH = (short*)xzB;
        short* xcH = (short*)xcB;
        short* dtH = (short*)dtBf;

        // xz(bf16) = x @ in_w^T   (M=12544, N=768, K=192), direct bf16 out
        gemm_pk_kernel<64, 128><<<dim3(768 / 128, RTOT / 64, 1), 256, 0, stream>>>(
            xinH, wIn_l, nullptr, xzH, nullptr, RTOT, 2 * DINNER, DM, DM);
        // xc(bf16) = silu(causal depthwise conv(xs bf16)) — 4 channels/thread
        {
            size_t n = R * (DINNER / 4);
            conv_silu_kernel<<<dim3((unsigned)((n + 255) / 256)), 256, 0, stream>>>(
                xzH, conv_wl, conv_bl, xcH);
        }
        // fused xproj: [B,C -> projBC fp32 | dt -> softplus bf16]  (N=416, K=384)
        gemm_xproj_kernel<<<dim3(7, RTOT / 64), 256, 0, stream>>>(
            xcH, wCmb_l, projBC, dtH, dtb_l, RTOT, DINNER);
        // chunked scan; scanC emits y2 bf16 into dead hEnd region
        scanA_kernel<<<dim3(3, CHUNKS, BB), 128, 0, stream>>>(
            xcH, projBC, dtH, Alog_l, scratch, scratch + SCN);
        scanB_kernel<<<dim3((BB * DINNER * DSTATE + 255) / 256), 256, 0, stream>>>(
            scratch, scratch + SCN);
        scanC_kernel<<<dim3(3, CHUNKS, BB), 128, 0, stream>>>(
            xcH, projBC, dtH, scratch + SCN, Alog_l, Dv_l, xzH, y2h);
        // x_next(bf16) = y2 @ outw^T (M=12544, N=192, K=384), SK1 direct bf16 out
        gemm_pk_kernel<64, 64><<<dim3(DM / 64, RTOT / 64, 1), 256, 0, stream>>>(
            y2h, wOut_l, nullptr, xoutH, nullptr, RTOT, DM, DINNER, DINNER);

        float* t = xin; xin = xout; xout = t;
    }

    // final layernorm + mean over sequence (bf16 x)
    short* xfH = (short*)xin;
    ln_stats_kernel<<<dim3(RTOT / 4), 256, 0, stream>>>(xfH, stats);
    ln_mean_kernel<<<dim3((BB * DM + 255) / 256), 256, 0, stream>>>(
        xfH, stats, norm_w, norm_b, out);
}

// Round 16
// 2929.729 us; speedup vs baseline: 1.8537x; 1.0838x over previous
//
#include <hip/hip_runtime.h>
#include <hip/hip_bf16.h>
#include <math.h>

#define BB 64
#define IMG 224
#define PP 16
#define CIN 3
#define DM 192
#define DEPTH 24
#define DSTATE 16
#define DINNER 384
#define DTR 12
#define DCONV 4
#define NP 196              // (224/16)^2
#define RTOT (BB * NP)      // 12544 rows
#define CHUNKS 14
#define LC 14               // NP / CHUNKS
#define NCMB (2 * DSTATE + DINNER)   // 416 = B,C (32) + dt (384)

typedef short bf16x8 __attribute__((ext_vector_type(8)));
typedef float f32x4 __attribute__((ext_vector_type(4)));

__device__ inline unsigned short f2bf_rne(float f) {
    unsigned u = __float_as_uint(f);
    unsigned r = u + 0x7fffu + ((u >> 16) & 1u);
    return (unsigned short)(r >> 16);
}
__device__ inline float bf2f(unsigned short s) {
    return __uint_as_float(((unsigned)s) << 16);
}

// ---------------- im2col for patch embed, emitting bf16 ----------------
__global__ __launch_bounds__(256) void im2col_pack_kernel(const float* __restrict__ img,
                                                          short* __restrict__ colH) {
    size_t idx = (size_t)blockIdx.x * 256 + threadIdx.x;
    if (idx >= (size_t)RTOT * 768) return;
    int t = (int)(idx % 768);
    size_t r = idx / 768;
    int l = (int)(r % NP);
    int b = (int)(r / NP);
    int ph = l / 14, pw = l % 14;
    int ci = t / 256, rem = t % 256;
    int i = rem / 16, j = rem % 16;
    float v = img[(((size_t)b * CIN + ci) * IMG + ph * 16 + i) * IMG + pw * 16 + j];
    colH[idx] = (short)f2bf_rne(v);
}

// ---------------- weight pack: fp32[NE] -> bf16 ----------------
__global__ __launch_bounds__(256) void pack_w_kernel(const float* __restrict__ W,
                                                     short* __restrict__ Wh, int NE) {
    int i = blockIdx.x * 256 + threadIdx.x;
    if (i * 4 >= NE) return;
    float4 v = *(const float4*)&W[i * 4];
    short4 h;
    h.x = (short)f2bf_rne(v.x);
    h.y = (short)f2bf_rne(v.y);
    h.z = (short)f2bf_rne(v.z);
    h.w = (short)f2bf_rne(v.w);
    *(short4*)&Wh[i * 4] = h;
}

// ---------------- combined xproj weight: [DEPTH][416][384] bf16 ----------------
__global__ __launch_bounds__(256) void wcmb_kernel(const float* __restrict__ xpw,
                                                   const float* __restrict__ dtw,
                                                   short* __restrict__ wCmb) {
    int idx = blockIdx.x * 256 + threadIdx.x;
    if (idx >= DEPTH * NCMB * DINNER) return;
    int layer = idx / (NCMB * DINNER);
    int rem = idx % (NCMB * DINNER);
    int n = rem / DINNER;
    int k = rem % DINNER;
    const float* xp = xpw + (size_t)layer * 44 * DINNER;
    float v;
    if (n < 32) {
        v = xp[(DTR + n) * DINNER + k];
    } else {
        int d = n - 32;
        const float* w = dtw + ((size_t)layer * DINNER + d) * DTR;
        v = 0.f;
#pragma unroll
        for (int j = 0; j < DTR; j++) v += w[j] * xp[j * DINNER + k];
    }
    wCmb[idx] = (short)f2bf_rne(v);
}

// ---------------- bf16 MFMA GEMM, double-buffered LDS, 1 barrier/k-iter ----------------
template<int BM, int BN>
__global__ __launch_bounds__(256) void gemm_pk_kernel(const short* __restrict__ Ah,
                                                      const short* __restrict__ Bh,
                                                      float* __restrict__ C,
                                                      short* __restrict__ CBf,
                                                      const float* __restrict__ bias,
                                                      int M, int N, int K, int Kc) {
    constexpr int BK = 32;
    constexpr int LDSS = BK + 8;
    constexpr int WR = BM / 64;
    constexpr int WC = 4 / WR;
    constexpr int NJ = BN / WC / 16;
    constexpr int A8 = BM / 64;
    constexpr int B8 = BN / 64;
    __shared__ short As[2][BM * LDSS];
    __shared__ short Bs[2][BN * LDSS];

    const int tid = threadIdx.x;
    const int lane = tid & 63;
    const int wid = tid >> 6;
    const int wr = wid / WC, wc = wid % WC;
    const int row0 = blockIdx.y * BM, col0 = blockIdx.x * BN;
    const int kbase = blockIdx.z * Kc;
    const bf16x8 ZV = {0, 0, 0, 0, 0, 0, 0, 0};

    bf16x8 aPh[A8], bPh[B8];
    f32x4 acc[4][NJ] = {};

    auto loadG = [&](int k0) {
#pragma unroll
        for (int i = 0; i < A8; i++) {
            int lin = tid + i * 256;
            int r = lin >> 2, cg = (lin & 3) * 8;
            aPh[i] = *(const bf16x8*)&Ah[(size_t)(row0 + r) * K + k0 + cg];
        }
#pragma unroll
        for (int i = 0; i < B8; i++) {
            int lin = tid + i * 256;
            int r = lin >> 2, cg = (lin & 3) * 8;
            int n = col0 + r;
            bPh[i] = (n < N) ? *(const bf16x8*)&Bh[(size_t)n * K + k0 + cg] : ZV;
        }
    };
    auto storeLDS = [&](int p) {
#pragma unroll
        for (int i = 0; i < A8; i++) {
            int lin = tid + i * 256;
            int r = lin >> 2, cg = (lin & 3) * 8;
            *(bf16x8*)&As[p][r * LDSS + cg] = aPh[i];
        }
#pragma unroll
        for (int i = 0; i < B8; i++) {
            int lin = tid + i * 256;
            int r = lin >> 2, cg = (lin & 3) * 8;
            *(bf16x8*)&Bs[p][r * LDSS + cg] = bPh[i];
        }
    };
    auto compute = [&](int p) {
        const int fr = lane & 15;
        const int kg = (lane >> 4) * 8;
        bf16x8 aH[4], bH[NJ];
#pragma unroll
        for (int i = 0; i < 4; i++)
            aH[i] = *(const bf16x8*)&As[p][(wr * 64 + i * 16 + fr) * LDSS + kg];
#pragma unroll
        for (int j = 0; j < NJ; j++)
            bH[j] = *(const bf16x8*)&Bs[p][(wc * (BN / WC) + j * 16 + fr) * LDSS + kg];
#pragma unroll
        for (int i = 0; i < 4; i++)
#pragma unroll
            for (int j = 0; j < NJ; j++)
                acc[i][j] = __builtin_amdgcn_mfma_f32_16x16x32_bf16(aH[i], bH[j], acc[i][j], 0, 0, 0);
    };

    loadG(kbase);
    storeLDS(0);
    __syncthreads();
    int p = 0;
    for (int k0 = kbase + BK;; k0 += BK) {
        const bool has_next = (k0 < kbase + Kc);
        if (has_next) loadG(k0);
        compute(p);
        if (!has_next) break;
        storeLDS(p ^ 1);
        __syncthreads();
        p ^= 1;
    }

    const bool direct = (gridDim.z == 1);
    float* Cout = C + (size_t)blockIdx.z * M * N;
    const int crow = (lane >> 4) * 4;
    const int ccol = lane & 15;
#pragma unroll
    for (int i = 0; i < 4; i++)
#pragma unroll
        for (int j = 0; j < NJ; j++) {
            int gn = col0 + wc * (BN / WC) + j * 16 + ccol;
            if (gn >= N) continue;
            int gm0 = row0 + wr * 64 + i * 16 + crow;
            float bv = (direct && bias) ? bias[gn] : 0.f;
            if (direct && CBf) {
#pragma unroll
                for (int reg = 0; reg < 4; reg++)
                    CBf[(size_t)(gm0 + reg) * N + gn] = (short)f2bf_rne(acc[i][j][reg] + bv);
            } else {
#pragma unroll
                for (int reg = 0; reg < 4; reg++)
                    Cout[(size_t)(gm0 + reg) * N + gn] = acc[i][j][reg] + bv;
            }
        }
}

// ---------------- fused xproj GEMM (BM=64, BN=64, full coverage) ----------------
__global__ __launch_bounds__(256) void gemm_xproj_kernel(const short* __restrict__ Ah,
                                                         const short* __restrict__ Bh,
                                                         float* __restrict__ projBC,
                                                         short* __restrict__ dtB,
                                                         const float* __restrict__ dtb,
                                                         int M, int K) {
    constexpr int BM = 64, BN = 64, BK = 32;
    constexpr int LDSS = BK + 8;
    constexpr int N = NCMB;
    __shared__ short As[2][BM * LDSS];
    __shared__ short Bs[2][BN * LDSS];

    const int tid = threadIdx.x;
    const int lane = tid & 63;
    const int wc = tid >> 6;
    const int row0 = blockIdx.y * BM, col0 = blockIdx.x * BN;
    const bf16x8 ZV = {0, 0, 0, 0, 0, 0, 0, 0};

    bf16x8 aPh, bPh;
    f32x4 acc[4] = {};

    auto loadG = [&](int k0) {
        int r = tid >> 2, cg = (tid & 3) * 8;
        aPh = *(const bf16x8*)&Ah[(size_t)(row0 + r) * K + k0 + cg];
        int n = col0 + r;
        bPh = (n < N) ? *(const bf16x8*)&Bh[(size_t)n * K + k0 + cg] : ZV;
    };
    auto storeLDS = [&](int p) {
        int r = tid >> 2, cg = (tid & 3) * 8;
        *(bf16x8*)&As[p][r * LDSS + cg] = aPh;
        *(bf16x8*)&Bs[p][r * LDSS + cg] = bPh;
    };
    auto compute = [&](int p) {
        const int fr = lane & 15;
        const int kg = (lane >> 4) * 8;
        bf16x8 aH[4], bH;
#pragma unroll
        for (int i = 0; i < 4; i++)
            aH[i] = *(const bf16x8*)&As[p][(i * 16 + fr) * LDSS + kg];
        bH = *(const bf16x8*)&Bs[p][(wc * 16 + fr) * LDSS + kg];
#pragma unroll
        for (int i = 0; i < 4; i++)
            acc[i] = __builtin_amdgcn_mfma_f32_16x16x32_bf16(aH[i], bH, acc[i], 0, 0, 0);
    };

    loadG(0);
    storeLDS(0);
    __syncthreads();
    int p = 0;
    for (int k0 = BK;; k0 += BK) {
        const bool has_next = (k0 < K);
        if (has_next) loadG(k0);
        compute(p);
        if (!has_next) break;
        storeLDS(p ^ 1);
        __syncthreads();
        p ^= 1;
    }

    const int crow = (lane >> 4) * 4;
    const int ccol = lane & 15;
#pragma unroll
    for (int i = 0; i < 4; i++) {
        int gn = col0 + wc * 16 + ccol;
        if (gn >= NCMB) continue;
        int gm0 = row0 + i * 16 + crow;
        if (gn < 32) {
#pragma unroll
            for (int reg = 0; reg < 4; reg++)
                projBC[(size_t)(gm0 + reg) * 32 + gn] = acc[i][reg];
        } else {
            int d = gn - 32;
            float bv = dtb[d];
#pragma unroll
            for (int reg = 0; reg < 4; reg++) {
                float v = acc[i][reg] + bv;
                v = (v > 20.f) ? v : __logf(1.f + __expf(v));   // softplus
                dtB[(size_t)(gm0 + reg) * DINNER + d] = (short)f2bf_rne(v);
            }
        }
    }
}

// ---------------- split-K reduce (patch embed only) ----------------
__global__ __launch_bounds__(256) void reduce_kernel(const float* __restrict__ parts,
                                                     short* __restrict__ outH,
                                                     const float* __restrict__ bias,
                                                     long MN, int N, int SK) {
    long i = (long)blockIdx.x * 256 + threadIdx.x;
    if (i * 4 >= MN) return;
    float4 acc = *(const float4*)&parts[i * 4];
    for (int z = 1; z < SK; z++) {
        float4 v = *(const float4*)&parts[(size_t)z * MN + i * 4];
        acc.x += v.x; acc.y += v.y; acc.z += v.z; acc.w += v.w;
    }
    if (bias) {
        int col = (int)((i * 4) % N);
        float4 bv = *(const float4*)&bias[col];
        acc.x += bv.x; acc.y += bv.y; acc.z += bv.z; acc.w += bv.w;
    }
    short4 h;
    h.x = (short)f2bf_rne(acc.x);
    h.y = (short)f2bf_rne(acc.y);
    h.z = (short)f2bf_rne(acc.z);
    h.w = (short)f2bf_rne(acc.w);
    *(short4*)&outH[i * 4] = h;
}

// ---------------- causal depthwise conv + SiLU, 4 channels/thread ----------------
__global__ __launch_bounds__(256) void conv_silu_kernel(const short* __restrict__ xzBf,
                                                        const float* __restrict__ cw,
                                                        const float* __restrict__ cb,
                                                        short* __restrict__ xcH) {
    size_t idx = (size_t)blockIdx.x * 256 + threadIdx.x;
    if (idx >= (size_t)RTOT * (DINNER / 4)) return;
    int e0 = (int)(idx % (DINNER / 4)) * 4;
    size_t r = idx / (DINNER / 4);
    int l = (int)(r % NP);
    size_t b = r / NP;
    float acc[4];
    {
        float4 cbv = *(const float4*)&cb[e0];
        acc[0] = cbv.x; acc[1] = cbv.y; acc[2] = cbv.z; acc[3] = cbv.w;
    }
    float4 wv[4];
#pragma unroll
    for (int j = 0; j < 4; j++) wv[j] = *(const float4*)&cw[(e0 + j) * DCONV];
#pragma unroll
    for (int k = 0; k < DCONV; k++) {
        int ls = l + k - (DCONV - 1);
        if (ls >= 0) {
            short4 xv = *(const short4*)&xzBf[(b * NP + ls) * 768 + e0];
            acc[0] += bf2f((unsigned short)xv.x) * (&wv[0].x)[k];
            acc[1] += bf2f((unsigned short)xv.y) * (&wv[1].x)[k];
            acc[2] += bf2f((unsigned short)xv.z) * (&wv[2].x)[k];
            acc[3] += bf2f((unsigned short)xv.w) * (&wv[3].x)[k];
        }
    }
    short4 o;
#pragma unroll
    for (int j = 0; j < 4; j++) {
        float v = acc[j] / (1.f + __expf(-acc[j]));   // silu
        (&o.x)[j] = (short)f2bf_rne(v);
    }
    *(short4*)&xcH[r * DINNER + e0] = o;
}

// ---------------- chunked selective scan ----------------
// Per-lane a[s] from A_log. If a[s] == (s+1)*a0 (runtime-verified), dA[s] is a
// geometric chain from ONE exp; else generic 16-exp path. prodDA computed as
// exp(a[s]*sum(dt)) in both paths (prod of exps = exp of sum).
__global__ __launch_bounds__(128) void scanA_kernel(const short* __restrict__ xcB,
                                                    const float* __restrict__ projBC,
                                                    const short* __restrict__ dtB,
                                                    const float* __restrict__ A_log,
                                                    float* __restrict__ hEnd,
                                                    float* __restrict__ prodDA) {
    int d = blockIdx.x * 128 + threadIdx.x;       // grid.x = 3
    int c = blockIdx.y, b = blockIdx.z;
    float a[DSTATE], h[DSTATE];
#pragma unroll
    for (int s = 0; s < DSTATE; s++) {
        a[s] = -expf(A_log[(size_t)d * DSTATE + s]);   // precise (once per lane)
        h[s] = 0.f;
    }
    const float a0 = a[0];
    bool chain = true;
#pragma unroll
    for (int s = 1; s < DSTATE; s++)
        chain = chain && (fabsf(a[s] - (float)(s + 1) * a0) <= 1e-4f * fabsf(a[s]));
    float sdt = 0.f;
    size_t rbase = (size_t)b * NP + (size_t)c * LC;
    if (chain) {
        for (int l = 0; l < LC; l++) {
            size_t r = rbase + l;
            float dtv = bf2f((unsigned short)dtB[r * DINNER + d]);
            float du = dtv * bf2f((unsigned short)xcB[r * DINNER + d]);
            const float* pb = projBC + r * 32;
            float Bv[DSTATE];
            *(float4*)&Bv[0]  = *(const float4*)&pb[0];
            *(float4*)&Bv[4]  = *(const float4*)&pb[4];
            *(float4*)&Bv[8]  = *(const float4*)&pb[8];
            *(float4*)&Bv[12] = *(const float4*)&pb[12];
            float q = __expf(dtv * a0);
            float dA = q;
            h[0] = h[0] * dA + du * Bv[0];
#pragma unroll
            for (int s = 1; s < DSTATE; s++) {
                dA *= q;
                h[s] = h[s] * dA + du * Bv[s];
            }
            sdt += dtv;
        }
    } else {
        for (int l = 0; l < LC; l++) {
            size_t r = rbase + l;
            float dtv = bf2f((unsigned short)dtB[r * DINNER + d]);
            float du = dtv * bf2f((unsigned short)xcB[r * DINNER + d]);
            const float* pb = projBC + r * 32;
            float Bv[DSTATE];
            *(float4*)&Bv[0]  = *(const float4*)&pb[0];
            *(float4*)&Bv[4]  = *(const float4*)&pb[4];
            *(float4*)&Bv[8]  = *(const float4*)&pb[8];
            *(float4*)&Bv[12] = *(const float4*)&pb[12];
#pragma unroll
            for (int s = 0; s < DSTATE; s++) {
                float dA = __expf(dtv * a[s]);
                h[s] = h[s] * dA + du * Bv[s];
            }
            sdt += dtv;
        }
    }
    float* he = hEnd   + (((size_t)b * CHUNKS + c) * DINNER + d) * DSTATE;
    float* pd = prodDA + (((size_t)b * CHUNKS + c) * DINNER + d) * DSTATE;
#pragma unroll
    for (int g = 0; g < 4; g++)
        *(float4*)&he[g * 4] = *(float4*)&h[g * 4];
    float pv[DSTATE];
#pragma unroll
    for (int s = 0; s < DSTATE; s++) pv[s] = __expf(a[s] * sdt);   // prod(dA) = exp(a*sum dt)
#pragma unroll
    for (int g = 0; g < 4; g++)
        *(float4*)&pd[g * 4] = *(float4*)&pv[g * 4];
}

__global__ __launch_bounds__(256) void scanB_kernel(const float* __restrict__ hEnd,
                                                    float* __restrict__ prodDA) {
    int idx = blockIdx.x * 256 + threadIdx.x;
    if (idx >= BB * DINNER * DSTATE) return;
    int b = idx / (DINNER * DSTATE);
    int rem = idx % (DINNER * DSTATE);
    float run = 0.f;
    for (int c = 0; c < CHUNKS; c++) {
        size_t off = ((size_t)b * CHUNKS + c) * (DINNER * DSTATE) + rem;
        float p = prodDA[off];
        float e = hEnd[off];
        prodDA[off] = run;          // hInit for chunk c
        run = run * p + e;
    }
}

// Pass C: rerun from hInit; fused (y+u*D)*silu(z); emits y2 bf16.
__global__ __launch_bounds__(128) void scanC_kernel(const short* __restrict__ xcB,
                                                    const float* __restrict__ projBC,
                                                    const short* __restrict__ dtB,
                                                    const float* __restrict__ hInit,
                                                    const float* __restrict__ A_log,
                                                    const float* __restrict__ Dv,
                                                    const short* __restrict__ xzBf,
                                                    short* __restrict__ yh) {
    int d = blockIdx.x * 128 + threadIdx.x;       // grid.x = 3
    int c = blockIdx.y, b = blockIdx.z;
    float a[DSTATE], h[DSTATE];
#pragma unroll
    for (int s = 0; s < DSTATE; s++)
        a[s] = -expf(A_log[(size_t)d * DSTATE + s]);   // precise (once per lane)
    const float a0 = a[0];
    bool chain = true;
#pragma unroll
    for (int s = 1; s < DSTATE; s++)
        chain = chain && (fabsf(a[s] - (float)(s + 1) * a0) <= 1e-4f * fabsf(a[s]));
    const float* hi = hInit + (((size_t)b * CHUNKS + c) * DINNER + d) * DSTATE;
#pragma unroll
    for (int g = 0; g < 4; g++)
        *(float4*)&h[g * 4] = *(const float4*)&hi[g * 4];
    float Dd = Dv[d];
    size_t rbase = (size_t)b * NP + (size_t)c * LC;
    if (chain) {
        for (int l = 0; l < LC; l++) {
            size_t r = rbase + l;
            float dtv = bf2f((unsigned short)dtB[r * DINNER + d]);
            float u = bf2f((unsigned short)xcB[r * DINNER + d]);
            float du = dtv * u;
            const float* pb = projBC + r * 32;
            float Bv[DSTATE], Cv[DSTATE];
            *(float4*)&Bv[0]  = *(const float4*)&pb[0];
            *(float4*)&Bv[4]  = *(const float4*)&pb[4];
            *(float4*)&Bv[8]  = *(const float4*)&pb[8];
            *(float4*)&Bv[12] = *(const float4*)&pb[12];
            *(float4*)&Cv[0]  = *(const float4*)&pb[16];
            *(float4*)&Cv[4]  = *(const float4*)&pb[20];
            *(float4*)&Cv[8]  = *(const float4*)&pb[24];
            *(float4*)&Cv[12] = *(const float4*)&pb[28];
            float q = __expf(dtv * a0);
            float dA = q;
            h[0] = h[0] * dA + du * Bv[0];
            float y = h[0] * Cv[0];
#pragma unroll
            for (int s = 1; s < DSTATE; s++) {
                dA *= q;
                h[s] = h[s] * dA + du * Bv[s];
                y = fmaf(h[s], Cv[s], y);
            }
            float z = bf2f((unsigned short)xzBf[r * 768 + DINNER + d]);
            float val = (y + u * Dd) * (z / (1.f + __expf(-z)));
            yh[r * DINNER + d] = (short)f2bf_rne(val);
        }
    } else {
        for (int l = 0; l < LC; l++) {
            size_t r = rbase + l;
            float dtv = bf2f((unsigned short)dtB[r * DINNER + d]);
            float u = bf2f((unsigned short)xcB[r * DINNER + d]);
            float du = dtv * u;
            const float* pb = projBC + r * 32;
            float Bv[DSTATE], Cv[DSTATE];
            *(float4*)&Bv[0]  = *(const float4*)&pb[0];
            *(float4*)&Bv[4]  = *(const float4*)&pb[4];
            *(float4*)&Bv[8]  = *(const float4*)&pb[8];
            *(float4*)&Bv[12] = *(const float4*)&pb[12];
            *(float4*)&Cv[0]  = *(const float4*)&pb[16];
            *(float4*)&Cv[4]  = *(const float4*)&pb[20];
            *(float4*)&Cv[8]  = *(const float4*)&pb[24];
            *(float4*)&Cv[12] = *(const float4*)&pb[28];
            float y = 0.f;
#pragma unroll
            for (int s = 0; s < DSTATE; s++) {
                float dA = __expf(dtv * a[s]);
                h[s] = h[s] * dA + du * Bv[s];
                y = fmaf(h[s], Cv[s], y);
            }
            float z = bf2f((unsigned short)xzBf[r * 768 + DINNER + d]);
            float val = (y + u * Dd) * (z / (1.f + __expf(-z)));
            yh[r * DINNER + d] = (short)f2bf_rne(val);
        }
    }
}

// ---------------- final layernorm: per-row stats (bf16 x input) ----------------
__global__ __launch_bounds__(256) void ln_stats_kernel(const short* __restrict__ xh,
                                                       float* __restrict__ stats) {
    int r = blockIdx.x * 4 + (threadIdx.x >> 6);
    int lane = threadIdx.x & 63;
    if (r >= RTOT) return;
    float s = 0.f, ss = 0.f;
    for (int c = lane; c < DM; c += 64) {
        float v = bf2f((unsigned short)xh[(size_t)r * DM + c]);
        s += v;
        ss += v * v;
    }
#pragma unroll
    for (int o = 32; o > 0; o >>= 1) {
        s += __shfl_down(s, o);
        ss += __shfl_down(ss, o);
    }
    if (lane == 0) {
        float mu = s / (float)DM;
        float var = ss / (float)DM - mu * mu;
        stats[r * 2] = mu;
        stats[r * 2 + 1] = rsqrtf(var + 1e-5f);
    }
}

// ---------------- normalized mean over sequence (bf16 x input) ----------------
__global__ __launch_bounds__(256) void ln_mean_kernel(const short* __restrict__ xh,
                                                      const float* __restrict__ stats,
                                                      const float* __restrict__ nw,
                                                      const float* __restrict__ nb,
                                                      float* __restrict__ out) {
    int idx = blockIdx.x * 256 + threadIdx.x;
    if (idx >= BB * DM) return;
    int c = idx % DM;
    int b = idx / DM;
    float acc = 0.f;
    for (int l = 0; l < NP; l++) {
        size_t r = (size_t)b * NP + l;
        float v = bf2f((unsigned short)xh[r * DM + c]);
        acc += (v - stats[r * 2]) * stats[r * 2 + 1];
    }
    out[idx] = acc * (1.f / (float)NP) * nw[c] + nb[c];
}

extern "C" void kernel_launch(void* const* d_in, const int* in_sizes, int n_in,
                              void* d_out, int out_size, void* d_ws, size_t ws_size,
                              hipStream_t stream) {
    const float* img     = (const float*)d_in[0];
    const float* patch_w = (const float*)d_in[1];
    const float* patch_b = (const float*)d_in[2];
    const float* in_w    = (const float*)d_in[3];
    const float* conv_w  = (const float*)d_in[4];
    const float* conv_b  = (const float*)d_in[5];
    const float* xpw     = (const float*)d_in[6];
    const float* dtw     = (const float*)d_in[7];
    const float* dtb     = (const float*)d_in[8];
    const float* A_log   = (const float*)d_in[9];
    const float* Dv      = (const float*)d_in[10];
    const float* outw    = (const float*)d_in[11];
    const float* norm_w  = (const float*)d_in[12];
    const float* norm_b  = (const float*)d_in[13];
    float* out = (float*)d_out;

    float* ws = (float*)d_ws;
    const size_t R = RTOT;
    const size_t SCN = (size_t)BB * CHUNKS * DINNER * DSTATE;   // 5,505,024 fu

    float* xA      = ws;                       // x bf16
    float* xB      = xA + R * DM / 2;
    float* xzB     = xB + R * DM / 2;          // xz bf16 (also im2col col)
    float* xcB     = xzB + R * 768 / 2;        // xc bf16
    float* dtBf    = xcB + R * DINNER / 2;     // dt bf16
    float* projBC  = dtBf + R * DINNER / 2;    // R*32 fp32
    float* scratch = projBC + R * 32;          // 2*SCN shared (patch partials / hEnd+prodDA / y2)
    float* wAll    = scratch + 2 * SCN;        // packed weights
    float* stats   = wAll + 4644864;           // R*2

    short* wPatch = (short*)wAll;                           // 192*768
    short* wIn    = wPatch + (size_t)DM * 768;              // 24*768*192
    short* wOut   = wIn + (size_t)DEPTH * 2 * DINNER * DM;  // 24*192*384
    short* wCmb   = wOut + (size_t)DEPTH * DM * DINNER;     // 24*416*384

    short* y2h = (short*)scratch;              // y2 bf16 (dead hEnd region)

    // ---- pre-pack weights + build combined xproj/dt weight (once) ----
    pack_w_kernel<<<dim3((DM * 768 / 4 + 255) / 256), 256, 0, stream>>>(
        patch_w, wPatch, DM * 768);
    pack_w_kernel<<<dim3((DEPTH * 2 * DINNER * DM / 4 + 255) / 256), 256, 0, stream>>>(
        in_w, wIn, DEPTH * 2 * DINNER * DM);
    pack_w_kernel<<<dim3((DEPTH * DM * DINNER / 4 + 255) / 256), 256, 0, stream>>>(
        outw, wOut, DEPTH * DM * DINNER);
    wcmb_kernel<<<dim3((DEPTH * NCMB * DINNER + 255) / 256), 256, 0, stream>>>(
        xpw, dtw, wCmb);

    // ---- patch embed: bf16 im2col + SK4 GEMM + reduce(+bias) -> bf16 x ----
    {
        short* colH = (short*)xzB;
        size_t n = R * 768;
        im2col_pack_kernel<<<dim3((unsigned)((n + 255) / 256)), 256, 0, stream>>>(img, colH);
        gemm_pk_kernel<64, 64><<<dim3(3, RTOT / 64, 4), 256, 0, stream>>>(
            colH, wPatch, scratch, nullptr, nullptr, RTOT, DM, 768, 192);
        long MN = (long)RTOT * DM;
        reduce_kernel<<<dim3((unsigned)((MN / 4 + 255) / 256)), 256, 0, stream>>>(
            scratch, (short*)xA, patch_b, MN, DM, 4);
    }

    float* xin = xA;
    float* xout = xB;
    for (int layer = 0; layer < DEPTH; layer++) {
        const float* conv_wl = conv_w + (size_t)layer * DINNER * DCONV;
        const float* conv_bl = conv_b + (size_t)layer * DINNER;
        const float* dtb_l   = dtb + (size_t)layer * DINNER;
        const float* Alog_l  = A_log + (size_t)layer * DINNER * DSTATE;
        const float* Dv_l    = Dv + (size_t)layer * DINNER;
        short* wIn_l  = wIn + (size_t)layer * 2 * DINNER * DM;
        short* wOut_l = wOut + (size_t)layer * DM * DINNER;
        short* wCmb_l = wCmb + (size_t)layer * NCMB * DINNER;

        short* xinH = (short*)xin;
        short* xoutH = (short*)xout;
        short* xzH = (short*)xzB;
        short* xcH = (short*)xcB;
        short* dtH = (short*)dtBf;

        // xz(bf16) = x @ in_w^T   (M=12544, N=768, K=192), direct bf16 out
        gemm_pk_kernel<64, 128><<<dim3(768 / 128, RTOT / 64, 1), 256, 0, stream>>>(
            xinH, wIn_l, nullptr, xzH, nullptr, RTOT, 2 * DINNER, DM, DM);
        // xc(bf16) = silu(causal depthwise conv(xs bf16)) — 4 channels/thread
        {
            size_t n = R * (DINNER / 4);
            conv_silu_kernel<<<dim3((unsigned)((n + 255) / 256)), 256, 0, stream>>>(
                xzH, conv_wl, conv_bl, xcH);
        }
        // fused xproj: [B,C -> projBC fp32 | dt -> softplus bf16]  (N=416, K=384)
        gemm_xproj_kernel<<<dim3(7, RTOT / 64), 256, 0, stream>>>(
            xcH, wCmb_l, projBC, dtH, dtb_l, RTOT, DINNER);
        // chunked scan; scanC emits y2 bf16 into dead hEnd region
        scanA_kernel<<<dim3(3, CHUNKS, BB), 128, 0, stream>>>(
            xcH, projBC, dtH, Alog_l, scratch, scratch + SCN);
        scanB_kernel<<<dim3((BB * DINNER * DSTATE + 255) / 256), 256, 0, stream>>>(
            scratch, scratch + SCN);
        scanC_kernel<<<dim3(3, CHUNKS, BB), 128, 0, stream>>>(
            xcH, projBC, dtH, scratch + SCN, Alog_l, Dv_l, xzH, y2h);
        // x_next(bf16) = y2 @ outw^T (M=12544, N=192, K=384), SK1 direct bf16 out
        gemm_pk_kernel<64, 64><<<dim3(DM / 64, RTOT / 64, 1), 256, 0, stream>>>(
            y2h, wOut_l, nullptr, xoutH, nullptr, RTOT, DM, DINNER, DINNER);

        float* t = xin; xin = xout; xout = t;
    }

    // final layernorm + mean over sequence (bf16 x)
    short* xfH = (short*)xin;
    ln_stats_kernel<<<dim3(RTOT / 4), 256, 0, stream>>>(xfH, stats);
    ln_mean_kernel<<<dim3((BB * DM + 255) / 256), 256, 0, stream>>>(
        xfH, stats, norm_w, norm_b, out);
}